// Round 1
// baseline (853.134 us; speedup 1.0000x reference)
//
#include <hip/hip_runtime.h>
#include <cstdint>
#include <cstddef>

#define NN   50000
#define EEN  800000
#define INF_ 256
#define HH   3
#define FEAT 192   // H*D
#define EFD  64
#define NEG_ 0.2f
#define EPSF 1e-12f

static __device__ __forceinline__ float4 ld4(const float* p) {
    return *reinterpret_cast<const float4*>(p);
}

// ---------------- GEMM: C[M,N] = A[M,K] @ B[K,N], N%64==0, K%32==0 -------------
__global__ __launch_bounds__(256) void gemm_f32(const float* __restrict__ A,
        const float* __restrict__ B, float* __restrict__ C, int M, int N, int K)
{
    __shared__ __align__(16) float As[32][68];   // transposed A tile [k][m], row 272B (16B mult)
    __shared__ __align__(16) float Bs[32][64];
    const int t  = threadIdx.x;
    const int bm = blockIdx.x * 64, bn = blockIdx.y * 64;
    const int tr = t >> 4, tc = t & 15;
    const int lr = t >> 3;          // 0..31
    const int lk = (t & 7) * 4;     // 0,4,..,28
    const int rb = t >> 4;          // 0..15
    const int cb = (t & 15) * 4;
    float acc[4][4] = {};
    for (int k0 = 0; k0 < K; k0 += 32) {
        float4 a0 = make_float4(0.f,0.f,0.f,0.f), a1 = a0;
        int g0 = bm + lr, g1 = bm + lr + 32;
        if (g0 < M) a0 = ld4(A + (size_t)g0 * K + k0 + lk);
        if (g1 < M) a1 = ld4(A + (size_t)g1 * K + k0 + lk);
        As[lk+0][lr] = a0.x; As[lk+1][lr] = a0.y; As[lk+2][lr] = a0.z; As[lk+3][lr] = a0.w;
        As[lk+0][lr+32] = a1.x; As[lk+1][lr+32] = a1.y; As[lk+2][lr+32] = a1.z; As[lk+3][lr+32] = a1.w;
        float4 b0 = ld4(B + (size_t)(k0 + rb) * N + bn + cb);
        float4 b1 = ld4(B + (size_t)(k0 + rb + 16) * N + bn + cb);
        *reinterpret_cast<float4*>(&Bs[rb][cb])    = b0;
        *reinterpret_cast<float4*>(&Bs[rb+16][cb]) = b1;
        __syncthreads();
        #pragma unroll
        for (int k = 0; k < 32; ++k) {
            float4 av = *reinterpret_cast<const float4*>(&As[k][tr*4]);
            float4 bv = *reinterpret_cast<const float4*>(&Bs[k][tc*4]);
            float a[4] = {av.x, av.y, av.z, av.w};
            float b[4] = {bv.x, bv.y, bv.z, bv.w};
            #pragma unroll
            for (int i = 0; i < 4; ++i)
                #pragma unroll
                for (int j = 0; j < 4; ++j)
                    acc[i][j] += a[i] * b[j];
        }
        __syncthreads();
    }
    #pragma unroll
    for (int i = 0; i < 4; ++i) {
        int r = bm + tr*4 + i;
        if (r < M) {
            float4 v = make_float4(acc[i][0], acc[i][1], acc[i][2], acc[i][3]);
            *reinterpret_cast<float4*>(C + (size_t)r * N + bn + tc*4) = v;
        }
    }
}

// ---------------- CSR build --------------------------------------------------
__global__ void k_hist(const int* __restrict__ dst, int* __restrict__ deg) {
    int e = blockIdx.x * blockDim.x + threadIdx.x;
    if (e < EEN) atomicAdd(&deg[dst[e]], 1);
}

__global__ __launch_bounds__(1024) void k_scan(const int* __restrict__ deg,
        int* __restrict__ off, int* __restrict__ cur)
{
    __shared__ int wsums[16];
    __shared__ int wexc[16];
    __shared__ int tot;
    const int tid = threadIdx.x;
    const int lane = tid & 63, wid = tid >> 6;
    int carry = 0;
    for (int base = 0; base < NN; base += 1024) {
        int i = base + tid;
        int v = (i < NN) ? deg[i] : 0;
        int incl = v;
        #pragma unroll
        for (int o = 1; o < 64; o <<= 1) {
            int u = __shfl_up(incl, o);
            if (lane >= o) incl += u;
        }
        if (lane == 63) wsums[wid] = incl;
        __syncthreads();
        if (wid == 0) {
            int s = (lane < 16) ? wsums[lane] : 0;
            int si = s;
            #pragma unroll
            for (int o = 1; o < 16; o <<= 1) {
                int u = __shfl_up(si, o);
                if (lane >= o) si += u;
            }
            if (lane < 16) wexc[lane] = si - s;
            if (lane == 15) tot = si;
        }
        __syncthreads();
        int excl = carry + wexc[wid] + (incl - v);
        if (i < NN) { off[i] = excl; cur[i] = excl; }
        carry += tot;
        __syncthreads();
    }
    if (tid == 0) off[NN] = carry;
}

__global__ void k_scatter(const int* __restrict__ src, const int* __restrict__ dst,
        const int* __restrict__ et, int* __restrict__ cur, int* __restrict__ srcP)
{
    int e = blockIdx.x * blockDim.x + threadIdx.x;
    if (e < EEN) {
        int p = atomicAdd(&cur[dst[e]], 1);
        srcP[p] = src[e] | (et[e] << 27);
    }
}

// ---------------- per-edge-type attention bias table (8x3) -------------------
__global__ void k_eetab(const float* __restrict__ Eemb, const float* __restrict__ We,
                        const float* __restrict__ ae, float* __restrict__ eetab)
{
    int tid = threadIdx.x;
    if (tid < 24) {
        int tt = tid / 3, hh = tid % 3;
        float acc = 0.f;
        for (int f = 0; f < EFD; ++f) {
            float m = 0.f;
            for (int g = 0; g < EFD; ++g)
                m += Eemb[tt*EFD + g] * We[g*FEAT + hh*EFD + f];
            acc += m * ae[hh*EFD + f];
        }
        eetab[tt*3 + hh] = acc;
    }
}

// ---------------- el/er projections (wave per node) --------------------------
__global__ __launch_bounds__(256) void k_elr(const float* __restrict__ feat,
        const float* __restrict__ al, const float* __restrict__ ar,
        float* __restrict__ el, float* __restrict__ er)
{
    int wid = threadIdx.x >> 6, lane = threadIdx.x & 63;
    int n = blockIdx.x * 4 + wid;
    if (n >= NN) return;
    const float* f = feat + (size_t)n * FEAT;
    float v0 = f[lane], v1 = f[64 + lane], v2 = f[128 + lane];
    float p[6];
    p[0] = v0*al[lane]; p[1] = v1*al[64+lane]; p[2] = v2*al[128+lane];
    p[3] = v0*ar[lane]; p[4] = v1*ar[64+lane]; p[5] = v2*ar[128+lane];
    #pragma unroll
    for (int o = 32; o > 0; o >>= 1)
        #pragma unroll
        for (int q = 0; q < 6; ++q) p[q] += __shfl_xor(p[q], o);
    if (lane == 0) {
        el[n*3+0] = p[0]; el[n*3+1] = p[1]; el[n*3+2] = p[2];
        er[n*3+0] = p[3]; er[n*3+1] = p[4]; er[n*3+2] = p[5];
    }
}

// ---------------- edge softmax over incoming edges (thread per node) ---------
__global__ void k_edgesoftmax(const int* __restrict__ off, const int* __restrict__ srcP,
        const float* __restrict__ el, const float* __restrict__ er,
        const float* __restrict__ eetab, float* __restrict__ aP)
{
    int n = blockIdx.x * blockDim.x + threadIdx.x;
    if (n >= NN) return;
    int beg = off[n], end = off[n+1];
    if (beg == end) return;
    float er0 = er[n*3+0], er1 = er[n*3+1], er2 = er[n*3+2];
    float m0 = -1e30f, m1 = -1e30f, m2 = -1e30f;
    for (int p = beg; p < end; ++p) {
        int sp = srcP[p];
        int s  = sp & 0x07FFFFFF;
        int tt = ((unsigned)sp) >> 27;
        float l0 = el[s*3+0] + er0 + eetab[tt*3+0];
        float l1 = el[s*3+1] + er1 + eetab[tt*3+1];
        float l2 = el[s*3+2] + er2 + eetab[tt*3+2];
        l0 = l0 > 0.f ? l0 : NEG_*l0;
        l1 = l1 > 0.f ? l1 : NEG_*l1;
        l2 = l2 > 0.f ? l2 : NEG_*l2;
        aP[p*3+0] = l0; aP[p*3+1] = l1; aP[p*3+2] = l2;
        m0 = fmaxf(m0, l0); m1 = fmaxf(m1, l1); m2 = fmaxf(m2, l2);
    }
    float d0 = 0.f, d1 = 0.f, d2 = 0.f;
    for (int p = beg; p < end; ++p) {
        float a0 = __expf(aP[p*3+0] - m0);
        float a1 = __expf(aP[p*3+1] - m1);
        float a2 = __expf(aP[p*3+2] - m2);
        aP[p*3+0] = a0; aP[p*3+1] = a1; aP[p*3+2] = a2;
        d0 += a0; d1 += a1; d2 += a2;
    }
    float i0 = 1.f / fmaxf(d0, EPSF);
    float i1 = 1.f / fmaxf(d1, EPSF);
    float i2 = 1.f / fmaxf(d2, EPSF);
    for (int p = beg; p < end; ++p) {
        aP[p*3+0] *= i0; aP[p*3+1] *= i1; aP[p*3+2] *= i2;
    }
}

// ---------------- aggregation (wave per node) + residual + ELU ---------------
template<bool RES>
__global__ __launch_bounds__(256) void k_aggregate(const int* __restrict__ off,
        const int* __restrict__ srcP, const float* __restrict__ aP,
        const float* __restrict__ feat, const float* __restrict__ res,
        float* __restrict__ out)
{
    int wid = threadIdx.x >> 6, lane = threadIdx.x & 63;
    int n = blockIdx.x * 4 + wid;
    if (n >= NN) return;
    int beg = off[n], end = off[n+1];
    float a0 = 0.f, a1 = 0.f, a2 = 0.f;
    for (int p = beg; p < end; ++p) {
        int s = srcP[p] & 0x07FFFFFF;
        float w0 = aP[p*3+0], w1 = aP[p*3+1], w2 = aP[p*3+2];
        const float* f = feat + (size_t)s * FEAT;
        a0 += w0 * f[lane];
        a1 += w1 * f[64 + lane];
        a2 += w2 * f[128 + lane];
    }
    if (RES) {
        const float* r = res + (size_t)n * FEAT;
        a0 += r[lane]; a1 += r[64 + lane]; a2 += r[128 + lane];
    }
    a0 = a0 > 0.f ? a0 : expm1f(a0);
    a1 = a1 > 0.f ? a1 : expm1f(a1);
    a2 = a2 > 0.f ? a2 : expm1f(a2);
    float* o = out + (size_t)n * FEAT;
    o[lane] = a0; o[64 + lane] = a1; o[128 + lane] = a2;
}

// ---------------- head-mean + L2 normalize -----------------------------------
__global__ __launch_bounds__(256) void k_final(const float* __restrict__ h,
                                               float* __restrict__ out)
{
    int wid = threadIdx.x >> 6, lane = threadIdx.x & 63;
    int n = blockIdx.x * 4 + wid;
    if (n >= NN) return;
    const float* f = h + (size_t)n * FEAT;
    float m = (f[lane] + f[64 + lane] + f[128 + lane]) * (1.f / 3.f);
    float ss = m * m;
    #pragma unroll
    for (int o = 32; o > 0; o >>= 1) ss += __shfl_xor(ss, o);
    float nrm = sqrtf(ss);
    out[(size_t)n * 64 + lane] = m / fmaxf(nrm, EPSF);
}

extern "C" void kernel_launch(void* const* d_in, const int* in_sizes, int n_in,
                              void* d_out, int out_size, void* d_ws, size_t ws_size,
                              hipStream_t stream)
{
    const float* x     = (const float*)d_in[0];
    const int*   src   = (const int*)d_in[1];
    const int*   dst   = (const int*)d_in[2];
    const int*   efeat = (const int*)d_in[3];
    const float* W1    = (const float*)d_in[4];
    const float* Eemb1 = (const float*)d_in[5];
    const float* We1   = (const float*)d_in[6];
    const float* al1   = (const float*)d_in[7];
    const float* ar1   = (const float*)d_in[8];
    const float* ae1   = (const float*)d_in[9];
    const float* W2    = (const float*)d_in[10];
    const float* Eemb2 = (const float*)d_in[11];
    const float* We2   = (const float*)d_in[12];
    const float* al2   = (const float*)d_in[13];
    const float* ar2   = (const float*)d_in[14];
    const float* ae2   = (const float*)d_in[15];
    const float* Wres2 = (const float*)d_in[16];

    char* w = (char*)d_ws;
    auto alloc = [&](size_t bytes) {
        char* p = w;
        w += (bytes + 255) & ~(size_t)255;
        return p;
    };
    float* feat = (float*)alloc((size_t)NN * FEAT * 4);
    float* hbuf = (float*)alloc((size_t)NN * FEAT * 4);
    float* res  = (float*)alloc((size_t)NN * FEAT * 4);
    float* aP   = (float*)alloc((size_t)EEN * 3 * 4);
    float* el   = (float*)alloc((size_t)NN * 3 * 4);
    float* er   = (float*)alloc((size_t)NN * 3 * 4);
    int*   deg  = (int*)alloc((size_t)NN * 4);
    int*   off  = (int*)alloc((size_t)(NN + 1) * 4);
    int*   cur  = (int*)alloc((size_t)NN * 4);
    int*   srcP = (int*)alloc((size_t)EEN * 4);
    float* ee1  = (float*)alloc(24 * 4);
    float* ee2  = (float*)alloc(24 * 4);

    hipMemsetAsync(deg, 0, (size_t)NN * 4, stream);

    const int eb  = (EEN + 255) / 256;
    const int nb4 = (NN + 3) / 4;
    k_hist<<<eb, 256, 0, stream>>>(dst, deg);
    k_scan<<<1, 1024, 0, stream>>>(deg, off, cur);
    k_scatter<<<eb, 256, 0, stream>>>(src, dst, efeat, cur, srcP);
    k_eetab<<<1, 64, 0, stream>>>(Eemb1, We1, ae1, ee1);
    k_eetab<<<1, 64, 0, stream>>>(Eemb2, We2, ae2, ee2);

    dim3 gg((NN + 63) / 64, FEAT / 64);
    // ---- layer 1 ----
    gemm_f32<<<gg, 256, 0, stream>>>(x, W1, feat, NN, FEAT, INF_);
    k_elr<<<nb4, 256, 0, stream>>>(feat, al1, ar1, el, er);
    k_edgesoftmax<<<(NN + 255) / 256, 256, 0, stream>>>(off, srcP, el, er, ee1, aP);
    k_aggregate<false><<<nb4, 256, 0, stream>>>(off, srcP, aP, feat, nullptr, hbuf);
    // ---- layer 2 ----
    gemm_f32<<<gg, 256, 0, stream>>>(hbuf, W2, feat, NN, FEAT, FEAT);
    gemm_f32<<<gg, 256, 0, stream>>>(hbuf, Wres2, res, NN, FEAT, FEAT);
    k_elr<<<nb4, 256, 0, stream>>>(feat, al2, ar2, el, er);
    k_edgesoftmax<<<(NN + 255) / 256, 256, 0, stream>>>(off, srcP, el, er, ee2, aP);
    k_aggregate<true><<<nb4, 256, 0, stream>>>(off, srcP, aP, feat, res, hbuf);
    // ---- head mean + normalize ----
    k_final<<<nb4, 256, 0, stream>>>(hbuf, (float*)d_out);
}

// Round 2
// 690.140 us; speedup vs baseline: 1.2362x; 1.2362x over previous
//
#include <hip/hip_runtime.h>
#include <cstdint>
#include <cstddef>

#define NN   50000
#define EEN  800000
#define INF_ 256
#define HH   3
#define FEAT 192   // H*D
#define EFD  64
#define NEG_ 0.2f
#define EPSF 1e-12f

typedef __attribute__((ext_vector_type(8))) short short8;
typedef __attribute__((ext_vector_type(4))) float f32x4;

static __device__ __forceinline__ float4 ld4(const float* p) {
    return *reinterpret_cast<const float4*>(p);
}
static __device__ __forceinline__ ushort f2b(float f) {
    union { float f; uint32_t u; } v; v.f = f;
    uint32_t u = v.u;
    return (ushort)((u + 0x7FFFu + ((u >> 16) & 1u)) >> 16);
}
static __device__ __forceinline__ float b2f(ushort h) {
    union { uint32_t u; float f; } v; v.u = ((uint32_t)h) << 16;
    return v.f;
}

// ---------------- f32 -> bf16 bulk convert -----------------------------------
__global__ __launch_bounds__(256) void k_f2b(const float* __restrict__ in,
        ushort* __restrict__ out, int n)
{
    int i = (blockIdx.x * blockDim.x + threadIdx.x) * 4;
    if (i + 3 < n) {
        float4 v = ld4(in + i);
        ushort4 o;
        o.x = f2b(v.x); o.y = f2b(v.y); o.z = f2b(v.z); o.w = f2b(v.w);
        *reinterpret_cast<ushort4*>(out + i) = o;
    } else {
        for (int j = i; j < n; ++j) out[j] = f2b(in[j]);
    }
}

// ---------------- weight transpose+convert: W[K][N] -> BT[N][K] bf16 ---------
__global__ __launch_bounds__(256) void k_wtrans(const float* __restrict__ W,
        ushort* __restrict__ BT, int K, int N)
{
    int idx = blockIdx.x * blockDim.x + threadIdx.x;
    if (idx < N * K) {
        int n = idx / K, k = idx - n * K;
        BT[idx] = f2b(W[(size_t)k * N + n]);
    }
}

// ---------------- MFMA GEMM: C[M,192] = A[M,K](bf16) @ BT[192,K](bf16)^T -----
// block tile 128x64, 4 waves, each wave 32 rows x 64 cols (2x4 16x16 frags)
#define LDA 40   // padded LDS row stride (ushort)
template<bool OUTF32>
__global__ __launch_bounds__(256) void gemm_mfma(const ushort* __restrict__ A,
        const ushort* __restrict__ BT, void* __restrict__ Cv, int M, int K)
{
    __shared__ ushort As[128 * LDA];
    __shared__ ushort Bs[64 * LDA];
    const int t = threadIdx.x;
    const int lane = t & 63, w = t >> 6;
    const int bm = blockIdx.x * 128, bn = blockIdx.y * 64;
    const int sr = t >> 2;             // 0..63 staging row
    const int sc = (t & 3) * 8;        // staging col (elements)
    const int fr = lane & 15;          // frag row
    const int fg = (lane >> 4) * 8;    // frag k-offset
    const int fq = lane >> 4;

    f32x4 acc[2][4];
    #pragma unroll
    for (int i = 0; i < 2; ++i)
        #pragma unroll
        for (int c = 0; c < 4; ++c)
            acc[i][c] = (f32x4){0.f, 0.f, 0.f, 0.f};

    for (int k0 = 0; k0 < K; k0 += 32) {
        uint4 av0 = make_uint4(0,0,0,0), av1 = av0;
        int r0 = bm + sr, r1 = bm + 64 + sr;
        if (r0 < M) av0 = *reinterpret_cast<const uint4*>(A + (size_t)r0 * K + k0 + sc);
        if (r1 < M) av1 = *reinterpret_cast<const uint4*>(A + (size_t)r1 * K + k0 + sc);
        *reinterpret_cast<uint4*>(As + sr * LDA + sc) = av0;
        *reinterpret_cast<uint4*>(As + (64 + sr) * LDA + sc) = av1;
        uint4 bv = *reinterpret_cast<const uint4*>(BT + (size_t)(bn + sr) * K + k0 + sc);
        *reinterpret_cast<uint4*>(Bs + sr * LDA + sc) = bv;
        __syncthreads();
        short8 afr[2], bfr[4];
        afr[0] = *reinterpret_cast<const short8*>(As + (w * 32 + fr) * LDA + fg);
        afr[1] = *reinterpret_cast<const short8*>(As + (w * 32 + 16 + fr) * LDA + fg);
        #pragma unroll
        for (int c = 0; c < 4; ++c)
            bfr[c] = *reinterpret_cast<const short8*>(Bs + (c * 16 + fr) * LDA + fg);
        #pragma unroll
        for (int i = 0; i < 2; ++i)
            #pragma unroll
            for (int c = 0; c < 4; ++c)
                acc[i][c] = __builtin_amdgcn_mfma_f32_16x16x32_bf16(
                    afr[i], bfr[c], acc[i][c], 0, 0, 0);
        __syncthreads();
    }
    #pragma unroll
    for (int i = 0; i < 2; ++i) {
        #pragma unroll
        for (int c = 0; c < 4; ++c) {
            #pragma unroll
            for (int j = 0; j < 4; ++j) {
                int row = bm + w * 32 + i * 16 + fq * 4 + j;
                int col = bn + c * 16 + fr;
                if (row < M) {
                    if (OUTF32)
                        ((float*)Cv)[(size_t)row * FEAT + col] = acc[i][c][j];
                    else
                        ((ushort*)Cv)[(size_t)row * FEAT + col] = f2b(acc[i][c][j]);
                }
            }
        }
    }
}

// ---------------- CSR build --------------------------------------------------
__global__ void k_hist(const int* __restrict__ dst, int* __restrict__ deg) {
    int e = blockIdx.x * blockDim.x + threadIdx.x;
    if (e < EEN) atomicAdd(&deg[dst[e]], 1);
}

__global__ __launch_bounds__(1024) void k_scan(const int* __restrict__ deg,
        int* __restrict__ off, int* __restrict__ cur)
{
    __shared__ int wsums[16];
    __shared__ int wexc[16];
    __shared__ int tot;
    const int tid = threadIdx.x;
    const int lane = tid & 63, wid = tid >> 6;
    int carry = 0;
    for (int base = 0; base < NN; base += 1024) {
        int i = base + tid;
        int v = (i < NN) ? deg[i] : 0;
        int incl = v;
        #pragma unroll
        for (int o = 1; o < 64; o <<= 1) {
            int u = __shfl_up(incl, o);
            if (lane >= o) incl += u;
        }
        if (lane == 63) wsums[wid] = incl;
        __syncthreads();
        if (wid == 0) {
            int s = (lane < 16) ? wsums[lane] : 0;
            int si = s;
            #pragma unroll
            for (int o = 1; o < 16; o <<= 1) {
                int u = __shfl_up(si, o);
                if (lane >= o) si += u;
            }
            if (lane < 16) wexc[lane] = si - s;
            if (lane == 15) tot = si;
        }
        __syncthreads();
        int excl = carry + wexc[wid] + (incl - v);
        if (i < NN) { off[i] = excl; cur[i] = excl; }
        carry += tot;
        __syncthreads();
    }
    if (tid == 0) off[NN] = carry;
}

__global__ void k_scatter(const int* __restrict__ src, const int* __restrict__ dst,
        const int* __restrict__ et, int* __restrict__ cur, int* __restrict__ srcP)
{
    int e = blockIdx.x * blockDim.x + threadIdx.x;
    if (e < EEN) {
        int p = atomicAdd(&cur[dst[e]], 1);
        srcP[p] = src[e] | (et[e] << 27);
    }
}

// ---------------- per-edge-type attention bias table (8x3) -------------------
__global__ void k_eetab(const float* __restrict__ Eemb, const float* __restrict__ We,
                        const float* __restrict__ ae, float* __restrict__ eetab)
{
    int tid = threadIdx.x;
    if (tid < 24) {
        int tt = tid / 3, hh = tid % 3;
        float acc = 0.f;
        for (int f = 0; f < EFD; ++f) {
            float m = 0.f;
            for (int g = 0; g < EFD; ++g)
                m += Eemb[tt*EFD + g] * We[g*FEAT + hh*EFD + f];
            acc += m * ae[hh*EFD + f];
        }
        eetab[tt*3 + hh] = acc;
    }
}

// ---------------- el/er projections (wave per node, bf16 feat) ---------------
__global__ __launch_bounds__(256) void k_elr(const ushort* __restrict__ featb,
        const float* __restrict__ al, const float* __restrict__ ar,
        float* __restrict__ el, float* __restrict__ er)
{
    int wid = threadIdx.x >> 6, lane = threadIdx.x & 63;
    int n = blockIdx.x * 4 + wid;
    if (n >= NN) return;
    const ushort* f = featb + (size_t)n * FEAT;
    float v0 = b2f(f[lane]), v1 = b2f(f[64 + lane]), v2 = b2f(f[128 + lane]);
    float p[6];
    p[0] = v0*al[lane]; p[1] = v1*al[64+lane]; p[2] = v2*al[128+lane];
    p[3] = v0*ar[lane]; p[4] = v1*ar[64+lane]; p[5] = v2*ar[128+lane];
    #pragma unroll
    for (int o = 32; o > 0; o >>= 1)
        #pragma unroll
        for (int q = 0; q < 6; ++q) p[q] += __shfl_xor(p[q], o);
    if (lane == 0) {
        el[n*3+0] = p[0]; el[n*3+1] = p[1]; el[n*3+2] = p[2];
        er[n*3+0] = p[3]; er[n*3+1] = p[4]; er[n*3+2] = p[5];
    }
}

// ---------------- edge softmax: write exp(l - max) and 1/den -----------------
__global__ void k_edgesoftmax(const int* __restrict__ off, const int* __restrict__ srcP,
        const float* __restrict__ el, const float* __restrict__ er,
        const float* __restrict__ eetab, float* __restrict__ aP,
        float* __restrict__ dinv)
{
    int n = blockIdx.x * blockDim.x + threadIdx.x;
    if (n >= NN) return;
    int beg = off[n], end = off[n+1];
    if (beg == end) return;
    float er0 = er[n*3+0], er1 = er[n*3+1], er2 = er[n*3+2];
    float m0 = -1e30f, m1 = -1e30f, m2 = -1e30f;
    for (int p = beg; p < end; ++p) {
        int sp = srcP[p];
        int s  = sp & 0x07FFFFFF;
        int tt = ((unsigned)sp) >> 27;
        float l0 = el[s*3+0] + er0 + eetab[tt*3+0];
        float l1 = el[s*3+1] + er1 + eetab[tt*3+1];
        float l2 = el[s*3+2] + er2 + eetab[tt*3+2];
        l0 = l0 > 0.f ? l0 : NEG_*l0;
        l1 = l1 > 0.f ? l1 : NEG_*l1;
        l2 = l2 > 0.f ? l2 : NEG_*l2;
        aP[p*3+0] = l0; aP[p*3+1] = l1; aP[p*3+2] = l2;
        m0 = fmaxf(m0, l0); m1 = fmaxf(m1, l1); m2 = fmaxf(m2, l2);
    }
    float d0 = 0.f, d1 = 0.f, d2 = 0.f;
    for (int p = beg; p < end; ++p) {
        float a0 = __expf(aP[p*3+0] - m0);
        float a1 = __expf(aP[p*3+1] - m1);
        float a2 = __expf(aP[p*3+2] - m2);
        aP[p*3+0] = a0; aP[p*3+1] = a1; aP[p*3+2] = a2;
        d0 += a0; d1 += a1; d2 += a2;
    }
    dinv[n*3+0] = 1.f / fmaxf(d0, EPSF);
    dinv[n*3+1] = 1.f / fmaxf(d1, EPSF);
    dinv[n*3+2] = 1.f / fmaxf(d2, EPSF);
}

// ---------------- aggregation (wave per node) + residual + ELU ---------------
template<bool RES, bool OUTBF>
__global__ __launch_bounds__(256) void k_aggregate(const int* __restrict__ off,
        const int* __restrict__ srcP, const float* __restrict__ aP,
        const float* __restrict__ dinv, const ushort* __restrict__ featb,
        const float* __restrict__ res, void* __restrict__ outv)
{
    int wid = threadIdx.x >> 6, lane = threadIdx.x & 63;
    int n = blockIdx.x * 4 + wid;
    if (n >= NN) return;
    int beg = off[n], end = off[n+1];
    float a0 = 0.f, a1 = 0.f, a2 = 0.f;
    for (int p = beg; p < end; ++p) {
        int s = srcP[p] & 0x07FFFFFF;
        float w0 = aP[p*3+0], w1 = aP[p*3+1], w2 = aP[p*3+2];
        const ushort* f = featb + (size_t)s * FEAT;
        a0 += w0 * b2f(f[lane]);
        a1 += w1 * b2f(f[64 + lane]);
        a2 += w2 * b2f(f[128 + lane]);
    }
    float i0 = dinv[n*3+0], i1 = dinv[n*3+1], i2 = dinv[n*3+2];
    a0 *= i0; a1 *= i1; a2 *= i2;
    if (RES) {
        const float* r = res + (size_t)n * FEAT;
        a0 += r[lane]; a1 += r[64 + lane]; a2 += r[128 + lane];
    }
    a0 = a0 > 0.f ? a0 : expm1f(a0);
    a1 = a1 > 0.f ? a1 : expm1f(a1);
    a2 = a2 > 0.f ? a2 : expm1f(a2);
    if (OUTBF) {
        ushort* o = (ushort*)outv + (size_t)n * FEAT;
        o[lane] = f2b(a0); o[64 + lane] = f2b(a1); o[128 + lane] = f2b(a2);
    } else {
        float* o = (float*)outv + (size_t)n * FEAT;
        o[lane] = a0; o[64 + lane] = a1; o[128 + lane] = a2;
    }
}

// ---------------- head-mean + L2 normalize -----------------------------------
__global__ __launch_bounds__(256) void k_final(const float* __restrict__ h,
                                               float* __restrict__ out)
{
    int wid = threadIdx.x >> 6, lane = threadIdx.x & 63;
    int n = blockIdx.x * 4 + wid;
    if (n >= NN) return;
    const float* f = h + (size_t)n * FEAT;
    float m = (f[lane] + f[64 + lane] + f[128 + lane]) * (1.f / 3.f);
    float ss = m * m;
    #pragma unroll
    for (int o = 32; o > 0; o >>= 1) ss += __shfl_xor(ss, o);
    float nrm = sqrtf(ss);
    out[(size_t)n * 64 + lane] = m / fmaxf(nrm, EPSF);
}

extern "C" void kernel_launch(void* const* d_in, const int* in_sizes, int n_in,
                              void* d_out, int out_size, void* d_ws, size_t ws_size,
                              hipStream_t stream)
{
    const float* x     = (const float*)d_in[0];
    const int*   src   = (const int*)d_in[1];
    const int*   dst   = (const int*)d_in[2];
    const int*   efeat = (const int*)d_in[3];
    const float* W1    = (const float*)d_in[4];
    const float* Eemb1 = (const float*)d_in[5];
    const float* We1   = (const float*)d_in[6];
    const float* al1   = (const float*)d_in[7];
    const float* ar1   = (const float*)d_in[8];
    const float* ae1   = (const float*)d_in[9];
    const float* W2    = (const float*)d_in[10];
    const float* Eemb2 = (const float*)d_in[11];
    const float* We2   = (const float*)d_in[12];
    const float* al2   = (const float*)d_in[13];
    const float* ar2   = (const float*)d_in[14];
    const float* ae2   = (const float*)d_in[15];
    const float* Wres2 = (const float*)d_in[16];

    char* w = (char*)d_ws;
    auto alloc = [&](size_t bytes) {
        char* p = w;
        w += (bytes + 255) & ~(size_t)255;
        return p;
    };
    ushort* featb = (ushort*)alloc((size_t)NN * FEAT * 2);   // gemm out (bf16), reused both layers
    ushort* h1b   = (ushort*)alloc((size_t)NN * FEAT * 2);   // layer1 out (bf16)
    char*   u0    = alloc((size_t)NN * FEAT * 4);            // union: xb (25.6MB) | res (38.4MB)
    ushort* xb    = (ushort*)u0;
    float*  res   = (float*)u0;
    float*  h2    = (float*)alloc((size_t)NN * FEAT * 4);    // layer2 out (f32)
    float*  aP    = (float*)alloc((size_t)EEN * 3 * 4);
    float*  el    = (float*)alloc((size_t)NN * 3 * 4);
    float*  er    = (float*)alloc((size_t)NN * 3 * 4);
    float*  dinv  = (float*)alloc((size_t)NN * 3 * 4);
    int*    deg   = (int*)alloc((size_t)NN * 4);
    int*    off   = (int*)alloc((size_t)(NN + 1) * 4);
    int*    cur   = (int*)alloc((size_t)NN * 4);
    int*    srcP  = (int*)alloc((size_t)EEN * 4);
    ushort* w1bt  = (ushort*)alloc((size_t)FEAT * INF_ * 2);
    ushort* w2bt  = (ushort*)alloc((size_t)FEAT * FEAT * 2);
    ushort* wrbt  = (ushort*)alloc((size_t)FEAT * FEAT * 2);
    float*  ee1   = (float*)alloc(24 * 4);
    float*  ee2   = (float*)alloc(24 * 4);

    hipMemsetAsync(deg, 0, (size_t)NN * 4, stream);

    const int eb  = (EEN + 255) / 256;
    const int nb4 = (NN + 3) / 4;
    k_hist<<<eb, 256, 0, stream>>>(dst, deg);
    k_scan<<<1, 1024, 0, stream>>>(deg, off, cur);
    k_scatter<<<eb, 256, 0, stream>>>(src, dst, efeat, cur, srcP);
    k_eetab<<<1, 64, 0, stream>>>(Eemb1, We1, ae1, ee1);
    k_eetab<<<1, 64, 0, stream>>>(Eemb2, We2, ae2, ee2);

    // conversions
    k_f2b<<<(NN * INF_ / 4 + 255) / 256, 256, 0, stream>>>(x, xb, NN * INF_);
    k_wtrans<<<(FEAT * INF_ + 255) / 256, 256, 0, stream>>>(W1, w1bt, INF_, FEAT);
    k_wtrans<<<(FEAT * FEAT + 255) / 256, 256, 0, stream>>>(W2, w2bt, FEAT, FEAT);
    k_wtrans<<<(FEAT * FEAT + 255) / 256, 256, 0, stream>>>(Wres2, wrbt, FEAT, FEAT);

    dim3 gg((NN + 127) / 128, FEAT / 64);
    // ---- layer 1 ----
    gemm_mfma<false><<<gg, 256, 0, stream>>>(xb, w1bt, featb, NN, INF_);
    k_elr<<<nb4, 256, 0, stream>>>(featb, al1, ar1, el, er);
    k_edgesoftmax<<<(NN + 255) / 256, 256, 0, stream>>>(off, srcP, el, er, ee1, aP, dinv);
    k_aggregate<false, true><<<nb4, 256, 0, stream>>>(off, srcP, aP, dinv, featb, nullptr, h1b);
    // ---- layer 2 ----
    gemm_mfma<false><<<gg, 256, 0, stream>>>(h1b, w2bt, featb, NN, FEAT);
    gemm_mfma<true><<<gg, 256, 0, stream>>>(h1b, wrbt, res, NN, FEAT);
    k_elr<<<nb4, 256, 0, stream>>>(featb, al2, ar2, el, er);
    k_edgesoftmax<<<(NN + 255) / 256, 256, 0, stream>>>(off, srcP, el, er, ee2, aP, dinv);
    k_aggregate<true, false><<<nb4, 256, 0, stream>>>(off, srcP, aP, dinv, featb, res, h2);
    // ---- head mean + normalize ----
    k_final<<<nb4, 256, 0, stream>>>(h2, (float*)d_out);
}

// Round 3
// 495.797 us; speedup vs baseline: 1.7207x; 1.3920x over previous
//
#include <hip/hip_runtime.h>
#include <cstdint>
#include <cstddef>

#define NN   50000
#define EEN  800000
#define INF_ 256
#define HH   3
#define FEAT 192   // H*D
#define EFD  64
#define NEG_ 0.2f
#define EPSF 1e-12f

typedef __attribute__((ext_vector_type(8))) short short8;
typedef __attribute__((ext_vector_type(4))) float f32x4;

static __device__ __forceinline__ float4 ld4(const float* p) {
    return *reinterpret_cast<const float4*>(p);
}
static __device__ __forceinline__ ushort f2b(float f) {
    union { float f; uint32_t u; } v; v.f = f;
    uint32_t u = v.u;
    return (ushort)((u + 0x7FFFu + ((u >> 16) & 1u)) >> 16);
}
static __device__ __forceinline__ float b2f(ushort h) {
    union { uint32_t u; float f; } v; v.u = ((uint32_t)h) << 16;
    return v.f;
}

// ---------------- f32 -> bf16 bulk convert -----------------------------------
__global__ __launch_bounds__(256) void k_f2b(const float* __restrict__ in,
        ushort* __restrict__ out, int n)
{
    int i = (blockIdx.x * blockDim.x + threadIdx.x) * 4;
    if (i + 3 < n) {
        float4 v = ld4(in + i);
        ushort4 o;
        o.x = f2b(v.x); o.y = f2b(v.y); o.z = f2b(v.z); o.w = f2b(v.w);
        *reinterpret_cast<ushort4*>(out + i) = o;
    } else {
        for (int j = i; j < n; ++j) out[j] = f2b(in[j]);
    }
}

// ---------------- weight transpose+convert: W[K][N] -> BT[N][K] bf16 ---------
__global__ __launch_bounds__(256) void k_wtrans(const float* __restrict__ W,
        ushort* __restrict__ BT, int K, int N)
{
    int idx = blockIdx.x * blockDim.x + threadIdx.x;
    if (idx < N * K) {
        int n = idx / K, k = idx - n * K;
        BT[idx] = f2b(W[(size_t)k * N + n]);
    }
}

// ---------------- MFMA GEMM: C[M,192] = A[M,K](bf16) @ BT[192,K](bf16)^T -----
// block tile 128 x 192 (full N), 4 waves, each wave 32 rows x 192 cols
#define LDA 40   // padded LDS row stride (ushort)
template<bool OUTF32>
__global__ __launch_bounds__(256) void gemm_mfma(const ushort* __restrict__ A,
        const ushort* __restrict__ BT, void* __restrict__ Cv, int M, int K)
{
    __shared__ ushort As[128 * LDA];
    __shared__ ushort Bs[192 * LDA];
    const int t = threadIdx.x;
    const int lane = t & 63, w = t >> 6;
    const int bm = blockIdx.x * 128;
    const int fr = lane & 15;          // frag row/col within 16
    const int fg = (lane >> 4) * 8;    // frag k-offset
    const int fq = lane >> 4;
    const int arow = t >> 1;           // 0..127
    const int acol = (t & 1) * 8;      // elem col 0 or 8 (plus +16 later)
    const int brow = t >> 2;           // 0..63
    const int bcol = (t & 3) * 8;      // elem col

    f32x4 acc[2][12];
    #pragma unroll
    for (int i = 0; i < 2; ++i)
        #pragma unroll
        for (int c = 0; c < 12; ++c)
            acc[i][c] = (f32x4){0.f, 0.f, 0.f, 0.f};

    const int ga = bm + arow;
    for (int k0 = 0; k0 < K; k0 += 32) {
        uint4 av0 = make_uint4(0,0,0,0), av1 = av0;
        if (ga < M) {
            av0 = *reinterpret_cast<const uint4*>(A + (size_t)ga * K + k0 + acol);
            av1 = *reinterpret_cast<const uint4*>(A + (size_t)ga * K + k0 + acol + 16);
        }
        *reinterpret_cast<uint4*>(As + arow * LDA + acol) = av0;
        *reinterpret_cast<uint4*>(As + arow * LDA + acol + 16) = av1;
        #pragma unroll
        for (int j = 0; j < 3; ++j) {
            uint4 bv = *reinterpret_cast<const uint4*>(BT + (size_t)(j * 64 + brow) * K + k0 + bcol);
            *reinterpret_cast<uint4*>(Bs + (j * 64 + brow) * LDA + bcol) = bv;
        }
        __syncthreads();
        short8 afr0 = *reinterpret_cast<const short8*>(As + (w * 32 + fr) * LDA + fg);
        short8 afr1 = *reinterpret_cast<const short8*>(As + (w * 32 + 16 + fr) * LDA + fg);
        #pragma unroll
        for (int c = 0; c < 12; ++c) {
            short8 bfr = *reinterpret_cast<const short8*>(Bs + (c * 16 + fr) * LDA + fg);
            acc[0][c] = __builtin_amdgcn_mfma_f32_16x16x32_bf16(afr0, bfr, acc[0][c], 0, 0, 0);
            acc[1][c] = __builtin_amdgcn_mfma_f32_16x16x32_bf16(afr1, bfr, acc[1][c], 0, 0, 0);
        }
        __syncthreads();
    }
    #pragma unroll
    for (int i = 0; i < 2; ++i) {
        #pragma unroll
        for (int j = 0; j < 4; ++j) {
            int row = bm + w * 32 + i * 16 + fq * 4 + j;
            if (row < M) {
                #pragma unroll
                for (int c = 0; c < 12; ++c) {
                    int col = c * 16 + fr;
                    if (OUTF32)
                        ((float*)Cv)[(size_t)row * FEAT + col] = acc[i][c][j];
                    else
                        ((ushort*)Cv)[(size_t)row * FEAT + col] = f2b(acc[i][c][j]);
                }
            }
        }
    }
}

// ---------------- CSR build --------------------------------------------------
__global__ void k_hist(const int* __restrict__ dst, int* __restrict__ deg) {
    int e = blockIdx.x * blockDim.x + threadIdx.x;
    if (e < EEN) atomicAdd(&deg[dst[e]], 1);
}

__global__ __launch_bounds__(1024) void k_scan(const int* __restrict__ deg,
        int* __restrict__ off, int* __restrict__ cur)
{
    __shared__ int wsums[16];
    __shared__ int wexc[16];
    __shared__ int tot;
    const int tid = threadIdx.x;
    const int lane = tid & 63, wid = tid >> 6;
    int carry = 0;
    for (int base = 0; base < NN; base += 1024) {
        int i = base + tid;
        int v = (i < NN) ? deg[i] : 0;
        int incl = v;
        #pragma unroll
        for (int o = 1; o < 64; o <<= 1) {
            int u = __shfl_up(incl, o);
            if (lane >= o) incl += u;
        }
        if (lane == 63) wsums[wid] = incl;
        __syncthreads();
        if (wid == 0) {
            int s = (lane < 16) ? wsums[lane] : 0;
            int si = s;
            #pragma unroll
            for (int o = 1; o < 16; o <<= 1) {
                int u = __shfl_up(si, o);
                if (lane >= o) si += u;
            }
            if (lane < 16) wexc[lane] = si - s;
            if (lane == 15) tot = si;
        }
        __syncthreads();
        int excl = carry + wexc[wid] + (incl - v);
        if (i < NN) { off[i] = excl; cur[i] = excl; }
        carry += tot;
        __syncthreads();
    }
    if (tid == 0) off[NN] = carry;
}

__global__ void k_scatter(const int* __restrict__ src, const int* __restrict__ dst,
        const int* __restrict__ et, int* __restrict__ cur, int* __restrict__ srcP)
{
    int e = blockIdx.x * blockDim.x + threadIdx.x;
    if (e < EEN) {
        int p = atomicAdd(&cur[dst[e]], 1);
        srcP[p] = src[e] | (et[e] << 27);
    }
}

// ---------------- per-edge-type attention bias table (8x3), parallel ---------
__global__ __launch_bounds__(192) void k_eetab(const float* __restrict__ Eemb,
        const float* __restrict__ We, const float* __restrict__ ae,
        float* __restrict__ eetab)
{
    __shared__ float t1[3 * 64];       // [h][g]
    const int t = threadIdx.x;         // 192 threads
    const int g = t & 63, h = t >> 6;
    const float* wrow = We + g * FEAT + h * EFD;
    const float* av   = ae + h * EFD;
    float s = 0.f;
    #pragma unroll 8
    for (int f = 0; f < EFD; ++f) s += wrow[f] * av[f];
    t1[h * 64 + g] = s;
    __syncthreads();
    if (t < 24) {
        int tt = t / 3, hh = t - tt * 3;
        float acc = 0.f;
        const float* em = Eemb + tt * EFD;
        const float* tv = t1 + hh * 64;
        #pragma unroll 8
        for (int g2 = 0; g2 < 64; ++g2) acc += em[g2] * tv[g2];
        eetab[tt * 3 + hh] = acc;
    }
}

// ---------------- el/er projections (wave per node, bf16 feat) ---------------
__global__ __launch_bounds__(256) void k_elr(const ushort* __restrict__ featb,
        const float* __restrict__ al, const float* __restrict__ ar,
        float* __restrict__ el, float* __restrict__ er)
{
    int wid = threadIdx.x >> 6, lane = threadIdx.x & 63;
    int n = blockIdx.x * 4 + wid;
    if (n >= NN) return;
    const ushort* f = featb + (size_t)n * FEAT;
    float v0 = b2f(f[lane]), v1 = b2f(f[64 + lane]), v2 = b2f(f[128 + lane]);
    float p[6];
    p[0] = v0*al[lane]; p[1] = v1*al[64+lane]; p[2] = v2*al[128+lane];
    p[3] = v0*ar[lane]; p[4] = v1*ar[64+lane]; p[5] = v2*ar[128+lane];
    #pragma unroll
    for (int o = 32; o > 0; o >>= 1)
        #pragma unroll
        for (int q = 0; q < 6; ++q) p[q] += __shfl_xor(p[q], o);
    if (lane == 0) {
        el[n*3+0] = p[0]; el[n*3+1] = p[1]; el[n*3+2] = p[2];
        er[n*3+0] = p[3]; er[n*3+1] = p[4]; er[n*3+2] = p[5];
    }
}

// ---------------- edge softmax: write exp(l - max) and 1/den -----------------
__global__ void k_edgesoftmax(const int* __restrict__ off, const int* __restrict__ srcP,
        const float* __restrict__ el, const float* __restrict__ er,
        const float* __restrict__ eetab, float* __restrict__ aP,
        float* __restrict__ dinv)
{
    int n = blockIdx.x * blockDim.x + threadIdx.x;
    if (n >= NN) return;
    int beg = off[n], end = off[n+1];
    if (beg == end) return;
    float er0 = er[n*3+0], er1 = er[n*3+1], er2 = er[n*3+2];
    float m0 = -1e30f, m1 = -1e30f, m2 = -1e30f;
    for (int p = beg; p < end; ++p) {
        int sp = srcP[p];
        int s  = sp & 0x07FFFFFF;
        int tt = ((unsigned)sp) >> 27;
        float l0 = el[s*3+0] + er0 + eetab[tt*3+0];
        float l1 = el[s*3+1] + er1 + eetab[tt*3+1];
        float l2 = el[s*3+2] + er2 + eetab[tt*3+2];
        l0 = l0 > 0.f ? l0 : NEG_*l0;
        l1 = l1 > 0.f ? l1 : NEG_*l1;
        l2 = l2 > 0.f ? l2 : NEG_*l2;
        aP[p*3+0] = l0; aP[p*3+1] = l1; aP[p*3+2] = l2;
        m0 = fmaxf(m0, l0); m1 = fmaxf(m1, l1); m2 = fmaxf(m2, l2);
    }
    float d0 = 0.f, d1 = 0.f, d2 = 0.f;
    for (int p = beg; p < end; ++p) {
        float a0 = __expf(aP[p*3+0] - m0);
        float a1 = __expf(aP[p*3+1] - m1);
        float a2 = __expf(aP[p*3+2] - m2);
        aP[p*3+0] = a0; aP[p*3+1] = a1; aP[p*3+2] = a2;
        d0 += a0; d1 += a1; d2 += a2;
    }
    dinv[n*3+0] = 1.f / fmaxf(d0, EPSF);
    dinv[n*3+1] = 1.f / fmaxf(d1, EPSF);
    dinv[n*3+2] = 1.f / fmaxf(d2, EPSF);
}

// ---------------- aggregation (wave per node) + residual + ELU ---------------
template<bool RES, bool OUTBF>
__global__ __launch_bounds__(256) void k_aggregate(const int* __restrict__ off,
        const int* __restrict__ srcP, const float* __restrict__ aP,
        const float* __restrict__ dinv, const ushort* __restrict__ featb,
        const float* __restrict__ res, void* __restrict__ outv)
{
    int wid = threadIdx.x >> 6, lane = threadIdx.x & 63;
    int n = blockIdx.x * 4 + wid;
    if (n >= NN) return;
    int beg = off[n], end = off[n+1];
    float a0 = 0.f, a1 = 0.f, a2 = 0.f;
    for (int p = beg; p < end; ++p) {
        int s = srcP[p] & 0x07FFFFFF;
        float w0 = aP[p*3+0], w1 = aP[p*3+1], w2 = aP[p*3+2];
        const ushort* f = featb + (size_t)s * FEAT;
        a0 += w0 * b2f(f[lane]);
        a1 += w1 * b2f(f[64 + lane]);
        a2 += w2 * b2f(f[128 + lane]);
    }
    float i0 = dinv[n*3+0], i1 = dinv[n*3+1], i2 = dinv[n*3+2];
    a0 *= i0; a1 *= i1; a2 *= i2;
    if (RES) {
        const float* r = res + (size_t)n * FEAT;
        a0 += r[lane]; a1 += r[64 + lane]; a2 += r[128 + lane];
    }
    a0 = a0 > 0.f ? a0 : expm1f(a0);
    a1 = a1 > 0.f ? a1 : expm1f(a1);
    a2 = a2 > 0.f ? a2 : expm1f(a2);
    if (OUTBF) {
        ushort* o = (ushort*)outv + (size_t)n * FEAT;
        o[lane] = f2b(a0); o[64 + lane] = f2b(a1); o[128 + lane] = f2b(a2);
    } else {
        float* o = (float*)outv + (size_t)n * FEAT;
        o[lane] = a0; o[64 + lane] = a1; o[128 + lane] = a2;
    }
}

// ---------------- head-mean + L2 normalize -----------------------------------
__global__ __launch_bounds__(256) void k_final(const float* __restrict__ h,
                                               float* __restrict__ out)
{
    int wid = threadIdx.x >> 6, lane = threadIdx.x & 63;
    int n = blockIdx.x * 4 + wid;
    if (n >= NN) return;
    const float* f = h + (size_t)n * FEAT;
    float m = (f[lane] + f[64 + lane] + f[128 + lane]) * (1.f / 3.f);
    float ss = m * m;
    #pragma unroll
    for (int o = 32; o > 0; o >>= 1) ss += __shfl_xor(ss, o);
    float nrm = sqrtf(ss);
    out[(size_t)n * 64 + lane] = m / fmaxf(nrm, EPSF);
}

extern "C" void kernel_launch(void* const* d_in, const int* in_sizes, int n_in,
                              void* d_out, int out_size, void* d_ws, size_t ws_size,
                              hipStream_t stream)
{
    const float* x     = (const float*)d_in[0];
    const int*   src   = (const int*)d_in[1];
    const int*   dst   = (const int*)d_in[2];
    const int*   efeat = (const int*)d_in[3];
    const float* W1    = (const float*)d_in[4];
    const float* Eemb1 = (const float*)d_in[5];
    const float* We1   = (const float*)d_in[6];
    const float* al1   = (const float*)d_in[7];
    const float* ar1   = (const float*)d_in[8];
    const float* ae1   = (const float*)d_in[9];
    const float* W2    = (const float*)d_in[10];
    const float* Eemb2 = (const float*)d_in[11];
    const float* We2   = (const float*)d_in[12];
    const float* al2   = (const float*)d_in[13];
    const float* ar2   = (const float*)d_in[14];
    const float* ae2   = (const float*)d_in[15];
    const float* Wres2 = (const float*)d_in[16];

    char* w = (char*)d_ws;
    auto alloc = [&](size_t bytes) {
        char* p = w;
        w += (bytes + 255) & ~(size_t)255;
        return p;
    };
    ushort* featb = (ushort*)alloc((size_t)NN * FEAT * 2);   // gemm out (bf16), reused both layers
    ushort* h1b   = (ushort*)alloc((size_t)NN * FEAT * 2);   // layer1 out (bf16)
    char*   u0    = alloc((size_t)NN * FEAT * 4);            // union: xb (25.6MB) | res (38.4MB)
    ushort* xb    = (ushort*)u0;
    float*  res   = (float*)u0;
    float*  h2    = (float*)alloc((size_t)NN * FEAT * 4);    // layer2 out (f32)
    float*  aP    = (float*)alloc((size_t)EEN * 3 * 4);
    float*  el    = (float*)alloc((size_t)NN * 3 * 4);
    float*  er    = (float*)alloc((size_t)NN * 3 * 4);
    float*  dinv  = (float*)alloc((size_t)NN * 3 * 4);
    int*    deg   = (int*)alloc((size_t)NN * 4);
    int*    off   = (int*)alloc((size_t)(NN + 1) * 4);
    int*    cur   = (int*)alloc((size_t)NN * 4);
    int*    srcP  = (int*)alloc((size_t)EEN * 4);
    ushort* w1bt  = (ushort*)alloc((size_t)FEAT * INF_ * 2);
    ushort* w2bt  = (ushort*)alloc((size_t)FEAT * FEAT * 2);
    ushort* wrbt  = (ushort*)alloc((size_t)FEAT * FEAT * 2);
    float*  ee1   = (float*)alloc(24 * 4);
    float*  ee2   = (float*)alloc(24 * 4);

    hipMemsetAsync(deg, 0, (size_t)NN * 4, stream);

    const int eb  = (EEN + 255) / 256;
    const int nb4 = (NN + 3) / 4;
    k_hist<<<eb, 256, 0, stream>>>(dst, deg);
    k_scan<<<1, 1024, 0, stream>>>(deg, off, cur);
    k_scatter<<<eb, 256, 0, stream>>>(src, dst, efeat, cur, srcP);
    k_eetab<<<1, 192, 0, stream>>>(Eemb1, We1, ae1, ee1);
    k_eetab<<<1, 192, 0, stream>>>(Eemb2, We2, ae2, ee2);

    // conversions
    k_f2b<<<(NN * INF_ / 4 + 255) / 256, 256, 0, stream>>>(x, xb, NN * INF_);
    k_wtrans<<<(FEAT * INF_ + 255) / 256, 256, 0, stream>>>(W1, w1bt, INF_, FEAT);
    k_wtrans<<<(FEAT * FEAT + 255) / 256, 256, 0, stream>>>(W2, w2bt, FEAT, FEAT);
    k_wtrans<<<(FEAT * FEAT + 255) / 256, 256, 0, stream>>>(Wres2, wrbt, FEAT, FEAT);

    dim3 gg((NN + 127) / 128, 1);
    // ---- layer 1 ----
    gemm_mfma<false><<<gg, 256, 0, stream>>>(xb, w1bt, featb, NN, INF_);
    k_elr<<<nb4, 256, 0, stream>>>(featb, al1, ar1, el, er);
    k_edgesoftmax<<<(NN + 255) / 256, 256, 0, stream>>>(off, srcP, el, er, ee1, aP, dinv);
    k_aggregate<false, true><<<nb4, 256, 0, stream>>>(off, srcP, aP, dinv, featb, nullptr, h1b);
    // ---- layer 2 ----
    gemm_mfma<false><<<gg, 256, 0, stream>>>(h1b, w2bt, featb, NN, FEAT);
    gemm_mfma<true><<<gg, 256, 0, stream>>>(h1b, wrbt, res, NN, FEAT);
    k_elr<<<nb4, 256, 0, stream>>>(featb, al2, ar2, el, er);
    k_edgesoftmax<<<(NN + 255) / 256, 256, 0, stream>>>(off, srcP, el, er, ee2, aP, dinv);
    k_aggregate<true, false><<<nb4, 256, 0, stream>>>(off, srcP, aP, dinv, featb, res, h2);
    // ---- head mean + normalize ----
    k_final<<<nb4, 256, 0, stream>>>(h2, (float*)d_out);
}

// Round 4
// 362.638 us; speedup vs baseline: 2.3526x; 1.3672x over previous
//
#include <hip/hip_runtime.h>
#include <cstdint>
#include <cstddef>

#define NN   50000
#define EEN  800000
#define INF_ 256
#define HH   3
#define FEAT 192   // H*D
#define EFD  64
#define NEG_ 0.2f
#define EPSF 1e-12f

typedef __attribute__((ext_vector_type(8))) short short8;
typedef __attribute__((ext_vector_type(4))) float f32x4;

static __device__ __forceinline__ float4 ld4(const float* p) {
    return *reinterpret_cast<const float4*>(p);
}
static __device__ __forceinline__ ushort f2b(float f) {
    union { float f; uint32_t u; } v; v.f = f;
    uint32_t u = v.u;
    return (ushort)((u + 0x7FFFu + ((u >> 16) & 1u)) >> 16);
}
static __device__ __forceinline__ float b2f(ushort h) {
    union { uint32_t u; float f; } v; v.u = ((uint32_t)h) << 16;
    return v.f;
}

// ---------------- f32 -> bf16 bulk convert -----------------------------------
__global__ __launch_bounds__(256) void k_f2b(const float* __restrict__ in,
        ushort* __restrict__ out, int n)
{
    int i = (blockIdx.x * blockDim.x + threadIdx.x) * 4;
    if (i + 3 < n) {
        float4 v = ld4(in + i);
        ushort4 o;
        o.x = f2b(v.x); o.y = f2b(v.y); o.z = f2b(v.z); o.w = f2b(v.w);
        *reinterpret_cast<ushort4*>(out + i) = o;
    } else {
        for (int j = i; j < n; ++j) out[j] = f2b(in[j]);
    }
}

// ---------------- weight transpose+convert: W[K][N] -> BT[N][K] bf16 ---------
__global__ __launch_bounds__(256) void k_wtrans(const float* __restrict__ W,
        ushort* __restrict__ BT, int K, int N)
{
    int idx = blockIdx.x * blockDim.x + threadIdx.x;
    if (idx < N * K) {
        int n = idx / K, k = idx - n * K;
        BT[idx] = f2b(W[(size_t)k * N + n]);
    }
}

// ---------------- MFMA GEMM: C[M,192] = A[M,K](bf16) @ BT[192,K](bf16)^T -----
// block tile 128 x 192 (full N), 4 waves, each wave 32 rows x 192 cols
#define LDA 40   // padded LDS row stride (ushort)
template<bool OUTF32>
__global__ __launch_bounds__(256) void gemm_mfma(const ushort* __restrict__ A,
        const ushort* __restrict__ BT, void* __restrict__ Cv, int M, int K)
{
    __shared__ ushort As[128 * LDA];
    __shared__ ushort Bs[192 * LDA];
    const int t = threadIdx.x;
    const int lane = t & 63, w = t >> 6;
    const int bm = blockIdx.x * 128;
    const int fr = lane & 15;          // frag row/col within 16
    const int fg = (lane >> 4) * 8;    // frag k-offset
    const int fq = lane >> 4;
    const int arow = t >> 1;           // 0..127
    const int acol = (t & 1) * 8;      // elem col 0 or 8 (plus +16 later)
    const int brow = t >> 2;           // 0..63
    const int bcol = (t & 3) * 8;      // elem col

    f32x4 acc[2][12];
    #pragma unroll
    for (int i = 0; i < 2; ++i)
        #pragma unroll
        for (int c = 0; c < 12; ++c)
            acc[i][c] = (f32x4){0.f, 0.f, 0.f, 0.f};

    const int ga = bm + arow;
    for (int k0 = 0; k0 < K; k0 += 32) {
        uint4 av0 = make_uint4(0,0,0,0), av1 = av0;
        if (ga < M) {
            av0 = *reinterpret_cast<const uint4*>(A + (size_t)ga * K + k0 + acol);
            av1 = *reinterpret_cast<const uint4*>(A + (size_t)ga * K + k0 + acol + 16);
        }
        *reinterpret_cast<uint4*>(As + arow * LDA + acol) = av0;
        *reinterpret_cast<uint4*>(As + arow * LDA + acol + 16) = av1;
        #pragma unroll
        for (int j = 0; j < 3; ++j) {
            uint4 bv = *reinterpret_cast<const uint4*>(BT + (size_t)(j * 64 + brow) * K + k0 + bcol);
            *reinterpret_cast<uint4*>(Bs + (j * 64 + brow) * LDA + bcol) = bv;
        }
        __syncthreads();
        short8 afr0 = *reinterpret_cast<const short8*>(As + (w * 32 + fr) * LDA + fg);
        short8 afr1 = *reinterpret_cast<const short8*>(As + (w * 32 + 16 + fr) * LDA + fg);
        #pragma unroll
        for (int c = 0; c < 12; ++c) {
            short8 bfr = *reinterpret_cast<const short8*>(Bs + (c * 16 + fr) * LDA + fg);
            acc[0][c] = __builtin_amdgcn_mfma_f32_16x16x32_bf16(afr0, bfr, acc[0][c], 0, 0, 0);
            acc[1][c] = __builtin_amdgcn_mfma_f32_16x16x32_bf16(afr1, bfr, acc[1][c], 0, 0, 0);
        }
        __syncthreads();
    }
    #pragma unroll
    for (int i = 0; i < 2; ++i) {
        #pragma unroll
        for (int j = 0; j < 4; ++j) {
            int row = bm + w * 32 + i * 16 + fq * 4 + j;
            if (row < M) {
                #pragma unroll
                for (int c = 0; c < 12; ++c) {
                    int col = c * 16 + fr;
                    if (OUTF32)
                        ((float*)Cv)[(size_t)row * FEAT + col] = acc[i][c][j];
                    else
                        ((ushort*)Cv)[(size_t)row * FEAT + col] = f2b(acc[i][c][j]);
                }
            }
        }
    }
}

// ---------------- CSR build --------------------------------------------------
__global__ void k_hist(const int* __restrict__ dst, int* __restrict__ deg) {
    int e = blockIdx.x * blockDim.x + threadIdx.x;
    if (e < EEN) atomicAdd(&deg[dst[e]], 1);
}

__global__ __launch_bounds__(1024) void k_scan(const int* __restrict__ deg,
        int* __restrict__ off, int* __restrict__ cur)
{
    __shared__ int wsums[16];
    __shared__ int wexc[16];
    __shared__ int tot;
    const int tid = threadIdx.x;
    const int lane = tid & 63, wid = tid >> 6;
    int carry = 0;
    for (int base = 0; base < NN; base += 1024) {
        int i = base + tid;
        int v = (i < NN) ? deg[i] : 0;
        int incl = v;
        #pragma unroll
        for (int o = 1; o < 64; o <<= 1) {
            int u = __shfl_up(incl, o);
            if (lane >= o) incl += u;
        }
        if (lane == 63) wsums[wid] = incl;
        __syncthreads();
        if (wid == 0) {
            int s = (lane < 16) ? wsums[lane] : 0;
            int si = s;
            #pragma unroll
            for (int o = 1; o < 16; o <<= 1) {
                int u = __shfl_up(si, o);
                if (lane >= o) si += u;
            }
            if (lane < 16) wexc[lane] = si - s;
            if (lane == 15) tot = si;
        }
        __syncthreads();
        int excl = carry + wexc[wid] + (incl - v);
        if (i < NN) { off[i] = excl; cur[i] = excl; }
        carry += tot;
        __syncthreads();
    }
    if (tid == 0) off[NN] = carry;
}

__global__ void k_scatter(const int* __restrict__ src, const int* __restrict__ dst,
        const int* __restrict__ et, int* __restrict__ cur, int* __restrict__ srcP)
{
    int e = blockIdx.x * blockDim.x + threadIdx.x;
    if (e < EEN) {
        int p = atomicAdd(&cur[dst[e]], 1);
        srcP[p] = src[e] | (et[e] << 27);
    }
}

// ---------------- per-edge-type attention bias table (8x3), parallel ---------
__global__ __launch_bounds__(192) void k_eetab(const float* __restrict__ Eemb,
        const float* __restrict__ We, const float* __restrict__ ae,
        float* __restrict__ eetab)
{
    __shared__ float t1[3 * 64];       // [h][g]
    const int t = threadIdx.x;         // 192 threads
    const int g = t & 63, h = t >> 6;
    const float* wrow = We + g * FEAT + h * EFD;
    const float* av   = ae + h * EFD;
    float s = 0.f;
    #pragma unroll 8
    for (int f = 0; f < EFD; ++f) s += wrow[f] * av[f];
    t1[h * 64 + g] = s;
    __syncthreads();
    if (t < 24) {
        int tt = t / 3, hh = t - tt * 3;
        float acc = 0.f;
        const float* em = Eemb + tt * EFD;
        const float* tv = t1 + hh * 64;
        #pragma unroll 8
        for (int g2 = 0; g2 < 64; ++g2) acc += em[g2] * tv[g2];
        eetab[tt * 3 + hh] = acc;
    }
}

// ---------------- el/er projections (wave per node, bf16 feat) ---------------
// writes el as padded float4 per node (gather-friendly), er as 3 floats
__global__ __launch_bounds__(256) void k_elr(const ushort* __restrict__ featb,
        const float* __restrict__ al, const float* __restrict__ ar,
        float4* __restrict__ el4, float* __restrict__ er)
{
    int wid = threadIdx.x >> 6, lane = threadIdx.x & 63;
    int n = blockIdx.x * 4 + wid;
    if (n >= NN) return;
    const ushort* f = featb + (size_t)n * FEAT;
    float v0 = b2f(f[lane]), v1 = b2f(f[64 + lane]), v2 = b2f(f[128 + lane]);
    float p[6];
    p[0] = v0*al[lane]; p[1] = v1*al[64+lane]; p[2] = v2*al[128+lane];
    p[3] = v0*ar[lane]; p[4] = v1*ar[64+lane]; p[5] = v2*ar[128+lane];
    #pragma unroll
    for (int o = 32; o > 0; o >>= 1)
        #pragma unroll
        for (int q = 0; q < 6; ++q) p[q] += __shfl_xor(p[q], o);
    if (lane == 0) {
        el4[n] = make_float4(p[0], p[1], p[2], 0.f);
        er[n*3+0] = p[3]; er[n*3+1] = p[4]; er[n*3+2] = p[5];
    }
}

// ---------------- fused edge-softmax + aggregation (wave per node) -----------
// feat rows read as 48 x ushort4; lane<48 owns 4 feature elems, head = lane>>4
template<bool RES, bool FINAL>
__global__ __launch_bounds__(256) void k_attn_agg(const int* __restrict__ off,
        const int* __restrict__ srcP, const float4* __restrict__ el4,
        const float* __restrict__ er, const float* __restrict__ eetab,
        const ushort4* __restrict__ feat4, const float4* __restrict__ res4,
        void* __restrict__ outv)
{
    __shared__ float4 sh[4][64];
    const int wid = threadIdx.x >> 6, lane = threadIdx.x & 63;
    const int n = blockIdx.x * 4 + wid;
    if (n >= NN) return;
    const int beg = off[n], end = off[n + 1];
    const int hd = lane >> 4;                  // 0..2 gather head; 3 = idle lanes
    float4* shw = sh[wid];

    const float er0 = er[n*3+0], er1 = er[n*3+1], er2 = er[n*3+2];
    float acc0 = 0.f, acc1 = 0.f, acc2 = 0.f, acc3 = 0.f;
    float m0 = -1e30f, m1 = -1e30f, m2 = -1e30f;
    float dl0 = 0.f, dl1 = 0.f, dl2 = 0.f;     // per-lane denominator partials

    for (int c0 = beg; c0 < end; c0 += 64) {
        const int e = c0 + lane;
        const bool valid = e < end;
        int s = 0;
        float l0 = -1e30f, l1 = -1e30f, l2 = -1e30f;
        if (valid) {
            int sp = srcP[e];
            s = sp & 0x07FFFFFF;
            int tt = ((unsigned)sp) >> 27;
            float4 ev = el4[s];
            l0 = ev.x + er0 + eetab[tt*3+0];
            l1 = ev.y + er1 + eetab[tt*3+1];
            l2 = ev.z + er2 + eetab[tt*3+2];
            l0 = l0 > 0.f ? l0 : NEG_ * l0;
            l1 = l1 > 0.f ? l1 : NEG_ * l1;
            l2 = l2 > 0.f ? l2 : NEG_ * l2;
        }
        // wave-wide max per head
        float c0m = l0, c1m = l1, c2m = l2;
        #pragma unroll
        for (int o = 32; o > 0; o >>= 1) {
            c0m = fmaxf(c0m, __shfl_xor(c0m, o));
            c1m = fmaxf(c1m, __shfl_xor(c1m, o));
            c2m = fmaxf(c2m, __shfl_xor(c2m, o));
        }
        const float nm0 = fmaxf(m0, c0m), nm1 = fmaxf(m1, c1m), nm2 = fmaxf(m2, c2m);
        const float sc0 = __expf(m0 - nm0), sc1 = __expf(m1 - nm1), sc2 = __expf(m2 - nm2);
        m0 = nm0; m1 = nm1; m2 = nm2;
        const float p0 = valid ? __expf(l0 - nm0) : 0.f;
        const float p1 = valid ? __expf(l1 - nm1) : 0.f;
        const float p2 = valid ? __expf(l2 - nm2) : 0.f;
        dl0 = dl0 * sc0 + p0; dl1 = dl1 * sc1 + p1; dl2 = dl2 * sc2 + p2;
        const float sch = hd == 0 ? sc0 : (hd == 1 ? sc1 : sc2);
        acc0 *= sch; acc1 *= sch; acc2 *= sch; acc3 *= sch;
        shw[lane] = make_float4(p0, p1, p2, __int_as_float(s));
        const int cnt = min(64, end - c0);
        int j = 0;
        for (; j + 4 <= cnt; j += 4) {
            float4 w0 = shw[j], w1 = shw[j+1], w2 = shw[j+2], w3 = shw[j+3];
            if (lane < 48) {
                int s0 = __float_as_int(w0.w), s1 = __float_as_int(w1.w);
                int s2 = __float_as_int(w2.w), s3 = __float_as_int(w3.w);
                ushort4 v0 = feat4[(size_t)s0 * 48 + lane];
                ushort4 v1 = feat4[(size_t)s1 * 48 + lane];
                ushort4 v2 = feat4[(size_t)s2 * 48 + lane];
                ushort4 v3 = feat4[(size_t)s3 * 48 + lane];
                float g0 = hd == 0 ? w0.x : (hd == 1 ? w0.y : w0.z);
                float g1 = hd == 0 ? w1.x : (hd == 1 ? w1.y : w1.z);
                float g2 = hd == 0 ? w2.x : (hd == 1 ? w2.y : w2.z);
                float g3 = hd == 0 ? w3.x : (hd == 1 ? w3.y : w3.z);
                acc0 += g0*b2f(v0.x) + g1*b2f(v1.x) + g2*b2f(v2.x) + g3*b2f(v3.x);
                acc1 += g0*b2f(v0.y) + g1*b2f(v1.y) + g2*b2f(v2.y) + g3*b2f(v3.y);
                acc2 += g0*b2f(v0.z) + g1*b2f(v1.z) + g2*b2f(v2.z) + g3*b2f(v3.z);
                acc3 += g0*b2f(v0.w) + g1*b2f(v1.w) + g2*b2f(v2.w) + g3*b2f(v3.w);
            }
        }
        for (; j < cnt; ++j) {
            float4 wv = shw[j];
            if (lane < 48) {
                int ss = __float_as_int(wv.w);
                float g = hd == 0 ? wv.x : (hd == 1 ? wv.y : wv.z);
                ushort4 v = feat4[(size_t)ss * 48 + lane];
                acc0 += g*b2f(v.x); acc1 += g*b2f(v.y);
                acc2 += g*b2f(v.z); acc3 += g*b2f(v.w);
            }
        }
    }
    // reduce denominators across the wave
    #pragma unroll
    for (int o = 32; o > 0; o >>= 1) {
        dl0 += __shfl_xor(dl0, o);
        dl1 += __shfl_xor(dl1, o);
        dl2 += __shfl_xor(dl2, o);
    }
    const float den = hd == 0 ? dl0 : (hd == 1 ? dl1 : dl2);
    const float inv = 1.f / fmaxf(den, EPSF);
    acc0 *= inv; acc1 *= inv; acc2 *= inv; acc3 *= inv;
    if (RES) {
        if (lane < 48) {
            float4 r = res4[(size_t)n * 48 + lane];
            acc0 += r.x; acc1 += r.y; acc2 += r.z; acc3 += r.w;
        }
    }
    acc0 = acc0 > 0.f ? acc0 : expm1f(acc0);
    acc1 = acc1 > 0.f ? acc1 : expm1f(acc1);
    acc2 = acc2 > 0.f ? acc2 : expm1f(acc2);
    acc3 = acc3 > 0.f ? acc3 : expm1f(acc3);
    if (!FINAL) {
        if (lane < 48) {
            ushort4 o4;
            o4.x = f2b(acc0); o4.y = f2b(acc1); o4.z = f2b(acc2); o4.w = f2b(acc3);
            ((ushort4*)outv)[(size_t)n * 48 + lane] = o4;
        }
    } else {
        // head mean: lane l (0..15) combines lanes l, l+16, l+32
        float b0 = __shfl(acc0, lane + 16), c0v = __shfl(acc0, lane + 32);
        float b1 = __shfl(acc1, lane + 16), c1v = __shfl(acc1, lane + 32);
        float b2 = __shfl(acc2, lane + 16), c2v = __shfl(acc2, lane + 32);
        float b3 = __shfl(acc3, lane + 16), c3v = __shfl(acc3, lane + 32);
        float mm0 = (acc0 + b0 + c0v) * (1.f / 3.f);
        float mm1 = (acc1 + b1 + c1v) * (1.f / 3.f);
        float mm2 = (acc2 + b2 + c2v) * (1.f / 3.f);
        float mm3 = (acc3 + b3 + c3v) * (1.f / 3.f);
        float ss = (lane < 16) ? (mm0*mm0 + mm1*mm1 + mm2*mm2 + mm3*mm3) : 0.f;
        #pragma unroll
        for (int o = 1; o < 16; o <<= 1) ss += __shfl_xor(ss, o);
        float nrm = sqrtf(ss);
        float invn = 1.f / fmaxf(nrm, EPSF);
        if (lane < 16) {
            ((float4*)outv)[(size_t)n * 16 + lane] =
                make_float4(mm0 * invn, mm1 * invn, mm2 * invn, mm3 * invn);
        }
    }
}

extern "C" void kernel_launch(void* const* d_in, const int* in_sizes, int n_in,
                              void* d_out, int out_size, void* d_ws, size_t ws_size,
                              hipStream_t stream)
{
    const float* x     = (const float*)d_in[0];
    const int*   src   = (const int*)d_in[1];
    const int*   dst   = (const int*)d_in[2];
    const int*   efeat = (const int*)d_in[3];
    const float* W1    = (const float*)d_in[4];
    const float* Eemb1 = (const float*)d_in[5];
    const float* We1   = (const float*)d_in[6];
    const float* al1   = (const float*)d_in[7];
    const float* ar1   = (const float*)d_in[8];
    const float* ae1   = (const float*)d_in[9];
    const float* W2    = (const float*)d_in[10];
    const float* Eemb2 = (const float*)d_in[11];
    const float* We2   = (const float*)d_in[12];
    const float* al2   = (const float*)d_in[13];
    const float* ar2   = (const float*)d_in[14];
    const float* ae2   = (const float*)d_in[15];
    const float* Wres2 = (const float*)d_in[16];

    char* w = (char*)d_ws;
    auto alloc = [&](size_t bytes) {
        char* p = w;
        w += (bytes + 255) & ~(size_t)255;
        return p;
    };
    ushort* featb = (ushort*)alloc((size_t)NN * FEAT * 2);   // gemm out (bf16)
    ushort* h1b   = (ushort*)alloc((size_t)NN * FEAT * 2);   // layer1 out (bf16)
    char*   u0    = alloc((size_t)NN * FEAT * 4);            // union: xb | res
    ushort* xb    = (ushort*)u0;
    float*  res   = (float*)u0;
    float4* el4   = (float4*)alloc((size_t)NN * 16);
    float*  er    = (float*)alloc((size_t)NN * 3 * 4);
    int*    deg   = (int*)alloc((size_t)NN * 4);
    int*    off   = (int*)alloc((size_t)(NN + 1) * 4);
    int*    cur   = (int*)alloc((size_t)NN * 4);
    int*    srcP  = (int*)alloc((size_t)EEN * 4);
    ushort* w1bt  = (ushort*)alloc((size_t)FEAT * INF_ * 2);
    ushort* w2bt  = (ushort*)alloc((size_t)FEAT * FEAT * 2);
    ushort* wrbt  = (ushort*)alloc((size_t)FEAT * FEAT * 2);
    float*  ee1   = (float*)alloc(24 * 4);
    float*  ee2   = (float*)alloc(24 * 4);

    hipMemsetAsync(deg, 0, (size_t)NN * 4, stream);

    const int eb  = (EEN + 255) / 256;
    const int nb4 = (NN + 3) / 4;
    k_hist<<<eb, 256, 0, stream>>>(dst, deg);
    k_scan<<<1, 1024, 0, stream>>>(deg, off, cur);
    k_scatter<<<eb, 256, 0, stream>>>(src, dst, efeat, cur, srcP);
    k_eetab<<<1, 192, 0, stream>>>(Eemb1, We1, ae1, ee1);
    k_eetab<<<1, 192, 0, stream>>>(Eemb2, We2, ae2, ee2);

    // conversions
    k_f2b<<<(NN * INF_ / 4 + 255) / 256, 256, 0, stream>>>(x, xb, NN * INF_);
    k_wtrans<<<(FEAT * INF_ + 255) / 256, 256, 0, stream>>>(W1, w1bt, INF_, FEAT);
    k_wtrans<<<(FEAT * FEAT + 255) / 256, 256, 0, stream>>>(W2, w2bt, FEAT, FEAT);
    k_wtrans<<<(FEAT * FEAT + 255) / 256, 256, 0, stream>>>(Wres2, wrbt, FEAT, FEAT);

    dim3 gg((NN + 127) / 128, 1);
    // ---- layer 1 ----
    gemm_mfma<false><<<gg, 256, 0, stream>>>(xb, w1bt, featb, NN, INF_);
    k_elr<<<nb4, 256, 0, stream>>>(featb, al1, ar1, el4, er);
    k_attn_agg<false, false><<<nb4, 256, 0, stream>>>(off, srcP, el4, er, ee1,
            (const ushort4*)featb, nullptr, h1b);
    // ---- layer 2 ----
    gemm_mfma<false><<<gg, 256, 0, stream>>>(h1b, w2bt, featb, NN, FEAT);
    gemm_mfma<true><<<gg, 256, 0, stream>>>(h1b, wrbt, res, NN, FEAT);
    k_elr<<<nb4, 256, 0, stream>>>(featb, al2, ar2, el4, er);
    k_attn_agg<true, true><<<nb4, 256, 0, stream>>>(off, srcP, el4, er, ee2,
            (const ushort4*)featb, (const float4*)res, (float*)d_out);
}

// Round 5
// 332.309 us; speedup vs baseline: 2.5673x; 1.0913x over previous
//
#include <hip/hip_runtime.h>
#include <cstdint>
#include <cstddef>

#define NN   50000
#define EEN  800000
#define INF_ 256
#define HH   3
#define FEAT 192   // H*D
#define EFD  64
#define NEG_ 0.2f
#define EPSF 1e-12f
#define SMASK 0x0FFFFFF0   // s*16 field in srcP

typedef __attribute__((ext_vector_type(8))) short short8;
typedef __attribute__((ext_vector_type(4))) float f32x4;

static __device__ __forceinline__ float4 ld4(const float* p) {
    return *reinterpret_cast<const float4*>(p);
}
static __device__ __forceinline__ uint f2b(float f) {
    union { float f; uint32_t u; } v; v.f = f;
    uint32_t u = v.u;
    return (u + 0x7FFFu + ((u >> 16) & 1u)) >> 16;
}
static __device__ __forceinline__ uint pack2(float a, float b) {
    return f2b(a) | (f2b(b) << 16);
}
static __device__ __forceinline__ float blo(uint u) {
    return __uint_as_float(u << 16);
}
static __device__ __forceinline__ float bhi(uint u) {
    return __uint_as_float(u & 0xFFFF0000u);
}

// ---------------- weight transpose+convert (all 3 weights, one launch) -------
__global__ __launch_bounds__(256) void k_wtrans3(const float* __restrict__ W1,
        ushort* __restrict__ o1, const float* __restrict__ W2,
        ushort* __restrict__ o2, const float* __restrict__ W3,
        ushort* __restrict__ o3)
{
    int idx = blockIdx.x * blockDim.x + threadIdx.x;
    if (idx < FEAT * INF_) {
        int n = idx / INF_, k = idx - n * INF_;
        o1[idx] = (ushort)f2b(W1[(size_t)k * FEAT + n]);
    } else if (idx < FEAT * INF_ + FEAT * FEAT) {
        int i = idx - FEAT * INF_;
        int n = i / FEAT, k = i - n * FEAT;
        o2[i] = (ushort)f2b(W2[(size_t)k * FEAT + n]);
    } else if (idx < FEAT * INF_ + 2 * FEAT * FEAT) {
        int i = idx - FEAT * INF_ - FEAT * FEAT;
        int n = i / FEAT, k = i - n * FEAT;
        o3[i] = (ushort)f2b(W3[(size_t)k * FEAT + n]);
    }
}

// ---------------- MFMA GEMM: C[M,192] = A[M,K] @ BT[192,K]^T -----------------
// block tile 128 x 192 (full N), 4 waves; optional fused el/er epilogue
#define LDA 40   // padded LDS row stride (ushort)
template<bool AF32, bool ELR, bool OUTF32>
__global__ __launch_bounds__(256) void gemm_mfma(const void* __restrict__ Av,
        const ushort* __restrict__ BT, void* __restrict__ Cv,
        float4* __restrict__ el4, float4* __restrict__ er4,
        const float* __restrict__ al, const float* __restrict__ ar,
        int M, int K)
{
    __shared__ ushort As[128 * LDA];
    __shared__ ushort Bs[192 * LDA];
    const int t = threadIdx.x;
    const int lane = t & 63, w = t >> 6;
    const int bm = blockIdx.x * 128;
    const int fr = lane & 15;
    const int fg = (lane >> 4) * 8;
    const int fq = lane >> 4;
    const int arow = t >> 1;           // 0..127
    const int acol = (t & 1) * 8;
    const int brow = t >> 2;           // 0..63
    const int bcol = (t & 3) * 8;

    f32x4 acc[2][12];
    #pragma unroll
    for (int i = 0; i < 2; ++i)
        #pragma unroll
        for (int c = 0; c < 12; ++c)
            acc[i][c] = (f32x4){0.f, 0.f, 0.f, 0.f};

    const int ga = bm + arow;
    for (int k0 = 0; k0 < K; k0 += 32) {
        uint4 u0 = make_uint4(0,0,0,0), u1 = u0;
        if (AF32) {
            const float* Af = (const float*)Av;
            if (ga < M) {
                const float* ap = Af + (size_t)ga * K + k0 + acol;
                float4 f0 = ld4(ap), f1 = ld4(ap + 4);
                float4 f2v = ld4(ap + 16), f3 = ld4(ap + 20);
                u0 = make_uint4(pack2(f0.x,f0.y), pack2(f0.z,f0.w),
                                pack2(f1.x,f1.y), pack2(f1.z,f1.w));
                u1 = make_uint4(pack2(f2v.x,f2v.y), pack2(f2v.z,f2v.w),
                                pack2(f3.x,f3.y), pack2(f3.z,f3.w));
            }
        } else {
            const ushort* Ab = (const ushort*)Av;
            if (ga < M) {
                u0 = *reinterpret_cast<const uint4*>(Ab + (size_t)ga * K + k0 + acol);
                u1 = *reinterpret_cast<const uint4*>(Ab + (size_t)ga * K + k0 + acol + 16);
            }
        }
        *reinterpret_cast<uint4*>(As + arow * LDA + acol) = u0;
        *reinterpret_cast<uint4*>(As + arow * LDA + acol + 16) = u1;
        #pragma unroll
        for (int j = 0; j < 3; ++j) {
            uint4 bv = *reinterpret_cast<const uint4*>(BT + (size_t)(j * 64 + brow) * K + k0 + bcol);
            *reinterpret_cast<uint4*>(Bs + (j * 64 + brow) * LDA + bcol) = bv;
        }
        __syncthreads();
        short8 afr0 = *reinterpret_cast<const short8*>(As + (w * 32 + fr) * LDA + fg);
        short8 afr1 = *reinterpret_cast<const short8*>(As + (w * 32 + 16 + fr) * LDA + fg);
        #pragma unroll
        for (int c = 0; c < 12; ++c) {
            short8 bfr = *reinterpret_cast<const short8*>(Bs + (c * 16 + fr) * LDA + fg);
            acc[0][c] = __builtin_amdgcn_mfma_f32_16x16x32_bf16(afr0, bfr, acc[0][c], 0, 0, 0);
            acc[1][c] = __builtin_amdgcn_mfma_f32_16x16x32_bf16(afr1, bfr, acc[1][c], 0, 0, 0);
        }
        __syncthreads();
    }
    #pragma unroll
    for (int i = 0; i < 2; ++i) {
        #pragma unroll
        for (int j = 0; j < 4; ++j) {
            int row = bm + w * 32 + i * 16 + fq * 4 + j;
            if (row < M) {
                #pragma unroll
                for (int c = 0; c < 12; ++c) {
                    int col = c * 16 + fr;
                    if (OUTF32)
                        ((float*)Cv)[(size_t)row * FEAT + col] = acc[i][c][j];
                    else
                        ((ushort*)Cv)[(size_t)row * FEAT + col] = (ushort)f2b(acc[i][c][j]);
                }
            }
        }
    }
    if (ELR) {
        float alv[12], arv[12];
        #pragma unroll
        for (int c = 0; c < 12; ++c) {
            alv[c] = al[c * 16 + fr];
            arv[c] = ar[c * 16 + fr];
        }
        #pragma unroll
        for (int i = 0; i < 2; ++i) {
            #pragma unroll
            for (int j = 0; j < 4; ++j) {
                int row = bm + w * 32 + i * 16 + fq * 4 + j;
                float pl0 = 0.f, pl1 = 0.f, pl2 = 0.f;
                float pr0 = 0.f, pr1 = 0.f, pr2 = 0.f;
                #pragma unroll
                for (int c = 0; c < 4; ++c)  { pl0 += acc[i][c][j]*alv[c];  pr0 += acc[i][c][j]*arv[c]; }
                #pragma unroll
                for (int c = 4; c < 8; ++c)  { pl1 += acc[i][c][j]*alv[c];  pr1 += acc[i][c][j]*arv[c]; }
                #pragma unroll
                for (int c = 8; c < 12; ++c) { pl2 += acc[i][c][j]*alv[c];  pr2 += acc[i][c][j]*arv[c]; }
                #pragma unroll
                for (int o = 1; o < 16; o <<= 1) {
                    pl0 += __shfl_xor(pl0, o); pl1 += __shfl_xor(pl1, o); pl2 += __shfl_xor(pl2, o);
                    pr0 += __shfl_xor(pr0, o); pr1 += __shfl_xor(pr1, o); pr2 += __shfl_xor(pr2, o);
                }
                if (fr == 0 && row < M) {
                    el4[row] = make_float4(pl0, pl1, pl2, 0.f);
                    er4[row] = make_float4(pr0, pr1, pr2, 0.f);
                }
            }
        }
    }
}

// ---------------- CSR build --------------------------------------------------
__global__ void k_hist(const int* __restrict__ dst, int* __restrict__ deg) {
    int e = blockIdx.x * blockDim.x + threadIdx.x;
    if (e < EEN) atomicAdd(&deg[dst[e]], 1);
}

__global__ __launch_bounds__(1024) void k_scan(const int* __restrict__ deg,
        int* __restrict__ off, int* __restrict__ cur)
{
    __shared__ int wsums[16];
    __shared__ int wexc[16];
    __shared__ int tot;
    const int tid = threadIdx.x;
    const int lane = tid & 63, wid = tid >> 6;
    int carry = 0;
    for (int base = 0; base < NN; base += 1024) {
        int i = base + tid;
        int v = (i < NN) ? deg[i] : 0;
        int incl = v;
        #pragma unroll
        for (int o = 1; o < 64; o <<= 1) {
            int u = __shfl_up(incl, o);
            if (lane >= o) incl += u;
        }
        if (lane == 63) wsums[wid] = incl;
        __syncthreads();
        if (wid == 0) {
            int s = (lane < 16) ? wsums[lane] : 0;
            int si = s;
            #pragma unroll
            for (int o = 1; o < 16; o <<= 1) {
                int u = __shfl_up(si, o);
                if (lane >= o) si += u;
            }
            if (lane < 16) wexc[lane] = si - s;
            if (lane == 15) tot = si;
        }
        __syncthreads();
        int excl = carry + wexc[wid] + (incl - v);
        if (i < NN) { off[i] = excl; cur[i] = excl; }
        carry += tot;
        __syncthreads();
    }
    if (tid == 0) off[NN] = carry;
}

__global__ void k_scatter(const int* __restrict__ src, const int* __restrict__ dst,
        const int* __restrict__ et, int* __restrict__ cur, int* __restrict__ srcP)
{
    int e = blockIdx.x * blockDim.x + threadIdx.x;
    if (e < EEN) {
        int p = atomicAdd(&cur[dst[e]], 1);
        srcP[p] = (src[e] << 4) | (et[e] << 28);
    }
}

// ---------------- per-edge-type attention bias table (8x3), parallel ---------
__global__ __launch_bounds__(192) void k_eetab(const float* __restrict__ Eemb,
        const float* __restrict__ We, const float* __restrict__ ae,
        float* __restrict__ eetab)
{
    __shared__ float t1[3 * 64];       // [h][g]
    const int t = threadIdx.x;         // 192 threads
    const int g = t & 63, h = t >> 6;
    const float* wrow = We + g * FEAT + h * EFD;
    const float* av   = ae + h * EFD;
    float s = 0.f;
    #pragma unroll 8
    for (int f = 0; f < EFD; ++f) s += wrow[f] * av[f];
    t1[h * 64 + g] = s;
    __syncthreads();
    if (t < 24) {
        int tt = t / 3, hh = t - tt * 3;
        float acc = 0.f;
        const float* em = Eemb + tt * EFD;
        const float* tv = t1 + hh * 64;
        #pragma unroll 8
        for (int g2 = 0; g2 < 64; ++g2) acc += em[g2] * tv[g2];
        eetab[tt * 3 + hh] = acc;
    }
}

// ---------------- fused edge-softmax + aggregation (wave per node) -----------
// srcP[e] = s*16 | et<<28 ; el4 gather offset = srcP & SMASK ; feat = that*24
template<bool RES, bool FINAL>
__global__ __launch_bounds__(256) void k_attn_agg(const int* __restrict__ off,
        const int* __restrict__ srcP, const float4* __restrict__ el4,
        const float4* __restrict__ er4, const float* __restrict__ eetab,
        const ushort* __restrict__ featb, const float4* __restrict__ res4,
        void* __restrict__ outv)
{
    __shared__ float4 sh[4][64];
    const int wid = threadIdx.x >> 6, lane = threadIdx.x & 63;
    const int n = blockIdx.x * 4 + wid;
    if (n >= NN) return;
    const int beg = off[n], end = off[n + 1];
    const int hd = lane >> 4;                  // 0..2 gather head; 3 = idle lanes
    const char* featc = (const char*)featb;
    const char* elc   = (const char*)el4;
    float4* shw = sh[wid];

    const float4 erv = er4[n];
    const float er0 = erv.x, er1 = erv.y, er2 = erv.z;
    float acc0 = 0.f, acc1 = 0.f, acc2 = 0.f, acc3 = 0.f;
    float m0 = -1e30f, m1 = -1e30f, m2 = -1e30f;
    float dl0 = 0.f, dl1 = 0.f, dl2 = 0.f;

    for (int c0 = beg; c0 < end; c0 += 64) {
        const int e = c0 + lane;
        const bool valid = e < end;
        int boff = 0;
        float l0 = -1e30f, l1 = -1e30f, l2 = -1e30f;
        if (valid) {
            int sp = srcP[e];
            int s16 = sp & SMASK;
            int tt = ((unsigned)sp) >> 28;
            float4 ev = *reinterpret_cast<const float4*>(elc + s16);
            l0 = ev.x + er0 + eetab[tt*3+0];
            l1 = ev.y + er1 + eetab[tt*3+1];
            l2 = ev.z + er2 + eetab[tt*3+2];
            l0 = l0 > 0.f ? l0 : NEG_ * l0;
            l1 = l1 > 0.f ? l1 : NEG_ * l1;
            l2 = l2 > 0.f ? l2 : NEG_ * l2;
            boff = s16 * 24;                  // = s*384 bytes into featb
        }
        float c0m = l0, c1m = l1, c2m = l2;
        #pragma unroll
        for (int o = 32; o > 0; o >>= 1) {
            c0m = fmaxf(c0m, __shfl_xor(c0m, o));
            c1m = fmaxf(c1m, __shfl_xor(c1m, o));
            c2m = fmaxf(c2m, __shfl_xor(c2m, o));
        }
        const float nm0 = fmaxf(m0, c0m), nm1 = fmaxf(m1, c1m), nm2 = fmaxf(m2, c2m);
        const float sc0 = __expf(m0 - nm0), sc1 = __expf(m1 - nm1), sc2 = __expf(m2 - nm2);
        m0 = nm0; m1 = nm1; m2 = nm2;
        const float p0 = valid ? __expf(l0 - nm0) : 0.f;
        const float p1 = valid ? __expf(l1 - nm1) : 0.f;
        const float p2 = valid ? __expf(l2 - nm2) : 0.f;
        dl0 = dl0 * sc0 + p0; dl1 = dl1 * sc1 + p1; dl2 = dl2 * sc2 + p2;
        const float sch = hd == 0 ? sc0 : (hd == 1 ? sc1 : sc2);
        acc0 *= sch; acc1 *= sch; acc2 *= sch; acc3 *= sch;
        shw[lane] = make_float4(p0, p1, p2, __int_as_float(boff));
        const int cnt = min(64, end - c0);
        int j = 0;
        for (; j + 4 <= cnt; j += 4) {
            float4 w0 = shw[j], w1 = shw[j+1], w2 = shw[j+2], w3 = shw[j+3];
            int b0 = __builtin_amdgcn_readfirstlane(__float_as_int(w0.w));
            int b1 = __builtin_amdgcn_readfirstlane(__float_as_int(w1.w));
            int b2 = __builtin_amdgcn_readfirstlane(__float_as_int(w2.w));
            int b3 = __builtin_amdgcn_readfirstlane(__float_as_int(w3.w));
            if (lane < 48) {
                uint2 u0 = reinterpret_cast<const uint2*>(featc + b0)[lane];
                uint2 u1 = reinterpret_cast<const uint2*>(featc + b1)[lane];
                uint2 u2 = reinterpret_cast<const uint2*>(featc + b2)[lane];
                uint2 u3 = reinterpret_cast<const uint2*>(featc + b3)[lane];
                float g0 = hd == 0 ? w0.x : (hd == 1 ? w0.y : w0.z);
                float g1 = hd == 0 ? w1.x : (hd == 1 ? w1.y : w1.z);
                float g2 = hd == 0 ? w2.x : (hd == 1 ? w2.y : w2.z);
                float g3 = hd == 0 ? w3.x : (hd == 1 ? w3.y : w3.z);
                acc0 += g0*blo(u0.x) + g1*blo(u1.x) + g2*blo(u2.x) + g3*blo(u3.x);
                acc1 += g0*bhi(u0.x) + g1*bhi(u1.x) + g2*bhi(u2.x) + g3*bhi(u3.x);
                acc2 += g0*blo(u0.y) + g1*blo(u1.y) + g2*blo(u2.y) + g3*blo(u3.y);
                acc3 += g0*bhi(u0.y) + g1*bhi(u1.y) + g2*bhi(u2.y) + g3*bhi(u3.y);
            }
        }
        for (; j < cnt; ++j) {
            float4 wv = shw[j];
            int bo = __builtin_amdgcn_readfirstlane(__float_as_int(wv.w));
            if (lane < 48) {
                uint2 u = reinterpret_cast<const uint2*>(featc + bo)[lane];
                float g = hd == 0 ? wv.x : (hd == 1 ? wv.y : wv.z);
                acc0 += g*blo(u.x); acc1 += g*bhi(u.x);
                acc2 += g*blo(u.y); acc3 += g*bhi(u.y);
            }
        }
    }
    #pragma unroll
    for (int o = 32; o > 0; o >>= 1) {
        dl0 += __shfl_xor(dl0, o);
        dl1 += __shfl_xor(dl1, o);
        dl2 += __shfl_xor(dl2, o);
    }
    const float den = hd == 0 ? dl0 : (hd == 1 ? dl1 : dl2);
    const float inv = 1.f / fmaxf(den, EPSF);
    acc0 *= inv; acc1 *= inv; acc2 *= inv; acc3 *= inv;
    if (RES) {
        if (lane < 48) {
            float4 r = res4[(size_t)n * 48 + lane];
            acc0 += r.x; acc1 += r.y; acc2 += r.z; acc3 += r.w;
        }
    }
    acc0 = acc0 > 0.f ? acc0 : expm1f(acc0);
    acc1 = acc1 > 0.f ? acc1 : expm1f(acc1);
    acc2 = acc2 > 0.f ? acc2 : expm1f(acc2);
    acc3 = acc3 > 0.f ? acc3 : expm1f(acc3);
    if (!FINAL) {
        if (lane < 48) {
            ushort4 o4;
            o4.x = (ushort)f2b(acc0); o4.y = (ushort)f2b(acc1);
            o4.z = (ushort)f2b(acc2); o4.w = (ushort)f2b(acc3);
            ((ushort4*)outv)[(size_t)n * 48 + lane] = o4;
        }
    } else {
        float b0 = __shfl(acc0, lane + 16), c0v = __shfl(acc0, lane + 32);
        float b1 = __shfl(acc1, lane + 16), c1v = __shfl(acc1, lane + 32);
        float b2 = __shfl(acc2, lane + 16), c2v = __shfl(acc2, lane + 32);
        float b3 = __shfl(acc3, lane + 16), c3v = __shfl(acc3, lane + 32);
        float mm0 = (acc0 + b0 + c0v) * (1.f / 3.f);
        float mm1 = (acc1 + b1 + c1v) * (1.f / 3.f);
        float mm2 = (acc2 + b2 + c2v) * (1.f / 3.f);
        float mm3 = (acc3 + b3 + c3v) * (1.f / 3.f);
        float ss = (lane < 16) ? (mm0*mm0 + mm1*mm1 + mm2*mm2 + mm3*mm3) : 0.f;
        #pragma unroll
        for (int o = 1; o < 16; o <<= 1) ss += __shfl_xor(ss, o);
        float nrm = sqrtf(ss);
        float invn = 1.f / fmaxf(nrm, EPSF);
        if (lane < 16) {
            ((float4*)outv)[(size_t)n * 16 + lane] =
                make_float4(mm0 * invn, mm1 * invn, mm2 * invn, mm3 * invn);
        }
    }
}

extern "C" void kernel_launch(void* const* d_in, const int* in_sizes, int n_in,
                              void* d_out, int out_size, void* d_ws, size_t ws_size,
                              hipStream_t stream)
{
    const float* x     = (const float*)d_in[0];
    const int*   src   = (const int*)d_in[1];
    const int*   dst   = (const int*)d_in[2];
    const int*   efeat = (const int*)d_in[3];
    const float* W1    = (const float*)d_in[4];
    const float* Eemb1 = (const float*)d_in[5];
    const float* We1   = (const float*)d_in[6];
    const float* al1   = (const float*)d_in[7];
    const float* ar1   = (const float*)d_in[8];
    const float* ae1   = (const float*)d_in[9];
    const float* W2    = (const float*)d_in[10];
    const float* Eemb2 = (const float*)d_in[11];
    const float* We2   = (const float*)d_in[12];
    const float* al2   = (const float*)d_in[13];
    const float* ar2   = (const float*)d_in[14];
    const float* ae2   = (const float*)d_in[15];
    const float* Wres2 = (const float*)d_in[16];

    char* w = (char*)d_ws;
    auto alloc = [&](size_t bytes) {
        char* p = w;
        w += (bytes + 255) & ~(size_t)255;
        return p;
    };
    ushort* featb = (ushort*)alloc((size_t)NN * FEAT * 2);   // gemm out (bf16)
    ushort* h1b   = (ushort*)alloc((size_t)NN * FEAT * 2);   // layer1 out (bf16)
    float*  res   = (float*)alloc((size_t)NN * FEAT * 4);    // residual (f32)
    float4* el4   = (float4*)alloc((size_t)NN * 16);
    float4* er4   = (float4*)alloc((size_t)NN * 16);
    int*    deg   = (int*)alloc((size_t)NN * 4);
    int*    off   = (int*)alloc((size_t)(NN + 1) * 4);
    int*    cur   = (int*)alloc((size_t)NN * 4);
    int*    srcP  = (int*)alloc((size_t)EEN * 4);
    ushort* w1bt  = (ushort*)alloc((size_t)FEAT * INF_ * 2);
    ushort* w2bt  = (ushort*)alloc((size_t)FEAT * FEAT * 2);
    ushort* wrbt  = (ushort*)alloc((size_t)FEAT * FEAT * 2);
    float*  ee1   = (float*)alloc(24 * 4);
    float*  ee2   = (float*)alloc(24 * 4);

    hipMemsetAsync(deg, 0, (size_t)NN * 4, stream);

    const int eb  = (EEN + 255) / 256;
    const int nb4 = (NN + 3) / 4;
    k_hist<<<eb, 256, 0, stream>>>(dst, deg);
    k_scan<<<1, 1024, 0, stream>>>(deg, off, cur);
    k_scatter<<<eb, 256, 0, stream>>>(src, dst, efeat, cur, srcP);
    k_eetab<<<1, 192, 0, stream>>>(Eemb1, We1, ae1, ee1);
    k_eetab<<<1, 192, 0, stream>>>(Eemb2, We2, ae2, ee2);
    const int wtot = FEAT * INF_ + 2 * FEAT * FEAT;
    k_wtrans3<<<(wtot + 255) / 256, 256, 0, stream>>>(W1, w1bt, W2, w2bt, Wres2, wrbt);

    dim3 gg((NN + 127) / 128, 1);
    // ---- layer 1 ----
    gemm_mfma<true, true, false><<<gg, 256, 0, stream>>>(x, w1bt, featb,
            el4, er4, al1, ar1, NN, INF_);
    k_attn_agg<false, false><<<nb4, 256, 0, stream>>>(off, srcP, el4, er4, ee1,
            featb, nullptr, h1b);
    // ---- layer 2 ----
    gemm_mfma<false, true, false><<<gg, 256, 0, stream>>>(h1b, w2bt, featb,
            el4, er4, al2, ar2, NN, FEAT);
    gemm_mfma<false, false, true><<<gg, 256, 0, stream>>>(h1b, wrbt, res,
            nullptr, nullptr, nullptr, nullptr, NN, FEAT);
    k_attn_agg<true, true><<<nb4, 256, 0, stream>>>(off, srcP, el4, er4, ee2,
            featb, (const float4*)res, (float*)d_out);
}

// Round 6
// 290.401 us; speedup vs baseline: 2.9378x; 1.1443x over previous
//
#include <hip/hip_runtime.h>
#include <cstdint>
#include <cstddef>

#define NN   50000
#define EEN  800000
#define INF_ 256
#define HH   3
#define FEAT 192   // H*D
#define EFD  64
#define NEG_ 0.2f
#define EPSF 1e-12f
#define SMASK 0x0FFFFFF0   // s*16 field in srcP
#define NB   ((NN + 1023) / 1024)

typedef __attribute__((ext_vector_type(8))) short short8;
typedef __attribute__((ext_vector_type(4))) float f32x4;

static __device__ __forceinline__ float4 ld4(const float* p) {
    return *reinterpret_cast<const float4*>(p);
}
static __device__ __forceinline__ uint f2b(float f) {
    union { float f; uint32_t u; } v; v.f = f;
    uint32_t u = v.u;
    return (u + 0x7FFFu + ((u >> 16) & 1u)) >> 16;
}
static __device__ __forceinline__ uint pack2(float a, float b) {
    return f2b(a) | (f2b(b) << 16);
}
static __device__ __forceinline__ float blo(uint u) {
    return __uint_as_float(u << 16);
}
static __device__ __forceinline__ float bhi(uint u) {
    return __uint_as_float(u & 0xFFFF0000u);
}

// ---------------- weight transpose+convert (all 3 weights, one launch) -------
__global__ __launch_bounds__(256) void k_wtrans3(const float* __restrict__ W1,
        ushort* __restrict__ o1, const float* __restrict__ W2,
        ushort* __restrict__ o2, const float* __restrict__ W3,
        ushort* __restrict__ o3)
{
    int idx = blockIdx.x * blockDim.x + threadIdx.x;
    if (idx < FEAT * INF_) {
        int n = idx / INF_, k = idx - n * INF_;
        o1[idx] = (ushort)f2b(W1[(size_t)k * FEAT + n]);
    } else if (idx < FEAT * INF_ + FEAT * FEAT) {
        int i = idx - FEAT * INF_;
        int n = i / FEAT, k = i - n * FEAT;
        o2[i] = (ushort)f2b(W2[(size_t)k * FEAT + n]);
    } else if (idx < FEAT * INF_ + 2 * FEAT * FEAT) {
        int i = idx - FEAT * INF_ - FEAT * FEAT;
        int n = i / FEAT, k = i - n * FEAT;
        o3[i] = (ushort)f2b(W3[(size_t)k * FEAT + n]);
    }
}

// ---------------- MFMA GEMM: 64-row tile, full-N(192), optional dual-B -------
// always computes el/er epilogue from the first (featb) product
#define LDA 40   // padded LDS row stride (ushort)
template<bool AF32, bool DUAL>
__global__ __launch_bounds__(256) void gemm_mfma(const void* __restrict__ Av,
        const ushort* __restrict__ BT, const ushort* __restrict__ BT2,
        ushort* __restrict__ Cb, ushort* __restrict__ resb,
        float4* __restrict__ el4, float4* __restrict__ er4,
        const float* __restrict__ al, const float* __restrict__ ar,
        int M, int K)
{
    __shared__ ushort As[64 * LDA];
    __shared__ ushort Bs[192 * LDA];
    __shared__ ushort Bs2[DUAL ? 192 * LDA : 16];
    const int t = threadIdx.x;
    const int lane = t & 63, w = t >> 6;
    const int bm = blockIdx.x * 64;
    const int fr = lane & 15;
    const int fq = lane >> 4;
    const int fg = fq * 8;
    const int arow = t >> 2;           // 0..63
    const int acol = (t & 3) * 8;
    const int brow = t >> 2;
    const int bcol = (t & 3) * 8;

    f32x4 acc[12], acc2[DUAL ? 12 : 1];
    #pragma unroll
    for (int c = 0; c < 12; ++c) acc[c] = (f32x4){0.f, 0.f, 0.f, 0.f};
    if (DUAL) {
        #pragma unroll
        for (int c = 0; c < 12; ++c) acc2[c] = (f32x4){0.f, 0.f, 0.f, 0.f};
    }

    const int ga = bm + arow;
    for (int k0 = 0; k0 < K; k0 += 32) {
        uint4 u0 = make_uint4(0,0,0,0);
        if (AF32) {
            if (ga < M) {
                const float* ap = (const float*)Av + (size_t)ga * K + k0 + acol;
                float4 f0 = ld4(ap), f1 = ld4(ap + 4);
                u0 = make_uint4(pack2(f0.x,f0.y), pack2(f0.z,f0.w),
                                pack2(f1.x,f1.y), pack2(f1.z,f1.w));
            }
        } else {
            if (ga < M)
                u0 = *reinterpret_cast<const uint4*>((const ushort*)Av + (size_t)ga * K + k0 + acol);
        }
        *reinterpret_cast<uint4*>(As + arow * LDA + acol) = u0;
        #pragma unroll
        for (int j = 0; j < 3; ++j) {
            uint4 bv = *reinterpret_cast<const uint4*>(BT + (size_t)(j * 64 + brow) * K + k0 + bcol);
            *reinterpret_cast<uint4*>(Bs + (j * 64 + brow) * LDA + bcol) = bv;
            if (DUAL) {
                uint4 b2 = *reinterpret_cast<const uint4*>(BT2 + (size_t)(j * 64 + brow) * K + k0 + bcol);
                *reinterpret_cast<uint4*>(Bs2 + (j * 64 + brow) * LDA + bcol) = b2;
            }
        }
        __syncthreads();
        short8 afr = *reinterpret_cast<const short8*>(As + (w * 16 + fr) * LDA + fg);
        #pragma unroll
        for (int c = 0; c < 12; ++c) {
            short8 bfr = *reinterpret_cast<const short8*>(Bs + (c * 16 + fr) * LDA + fg);
            acc[c] = __builtin_amdgcn_mfma_f32_16x16x32_bf16(afr, bfr, acc[c], 0, 0, 0);
            if (DUAL) {
                short8 b2 = *reinterpret_cast<const short8*>(Bs2 + (c * 16 + fr) * LDA + fg);
                acc2[c] = __builtin_amdgcn_mfma_f32_16x16x32_bf16(afr, b2, acc2[c], 0, 0, 0);
            }
        }
        __syncthreads();
    }
    #pragma unroll
    for (int j = 0; j < 4; ++j) {
        int row = bm + w * 16 + fq * 4 + j;
        if (row < M) {
            #pragma unroll
            for (int c = 0; c < 12; ++c) {
                Cb[(size_t)row * FEAT + c * 16 + fr] = (ushort)f2b(acc[c][j]);
                if (DUAL)
                    resb[(size_t)row * FEAT + c * 16 + fr] = (ushort)f2b(acc2[c][j]);
            }
        }
    }
    // fused el/er epilogue
    float alv[12], arv[12];
    #pragma unroll
    for (int c = 0; c < 12; ++c) {
        alv[c] = al[c * 16 + fr];
        arv[c] = ar[c * 16 + fr];
    }
    #pragma unroll
    for (int j = 0; j < 4; ++j) {
        int row = bm + w * 16 + fq * 4 + j;
        float pl0 = 0.f, pl1 = 0.f, pl2 = 0.f;
        float pr0 = 0.f, pr1 = 0.f, pr2 = 0.f;
        #pragma unroll
        for (int c = 0; c < 4; ++c)  { pl0 += acc[c][j]*alv[c];  pr0 += acc[c][j]*arv[c]; }
        #pragma unroll
        for (int c = 4; c < 8; ++c)  { pl1 += acc[c][j]*alv[c];  pr1 += acc[c][j]*arv[c]; }
        #pragma unroll
        for (int c = 8; c < 12; ++c) { pl2 += acc[c][j]*alv[c];  pr2 += acc[c][j]*arv[c]; }
        #pragma unroll
        for (int o = 1; o < 16; o <<= 1) {
            pl0 += __shfl_xor(pl0, o); pl1 += __shfl_xor(pl1, o); pl2 += __shfl_xor(pl2, o);
            pr0 += __shfl_xor(pr0, o); pr1 += __shfl_xor(pr1, o); pr2 += __shfl_xor(pr2, o);
        }
        if (fr == 0 && row < M) {
            el4[row] = make_float4(pl0, pl1, pl2, 0.f);
            er4[row] = make_float4(pr0, pr1, pr2, 0.f);
        }
    }
}

// ---------------- CSR build --------------------------------------------------
__global__ void k_hist(const int* __restrict__ dst, int* __restrict__ deg) {
    int e = blockIdx.x * blockDim.x + threadIdx.x;
    if (e < EEN) atomicAdd(&deg[dst[e]], 1);
}

__global__ __launch_bounds__(1024) void k_scan1(const int* __restrict__ deg,
        int* __restrict__ off, int* __restrict__ bsum)
{
    __shared__ int wsums[16];
    __shared__ int wexc[16];
    const int tid = threadIdx.x;
    const int lane = tid & 63, wid = tid >> 6;
    int i = blockIdx.x * 1024 + tid;
    int v = (i < NN) ? deg[i] : 0;
    int incl = v;
    #pragma unroll
    for (int o = 1; o < 64; o <<= 1) {
        int u = __shfl_up(incl, o);
        if (lane >= o) incl += u;
    }
    if (lane == 63) wsums[wid] = incl;
    __syncthreads();
    if (wid == 0) {
        int s = (lane < 16) ? wsums[lane] : 0;
        int si = s;
        #pragma unroll
        for (int o = 1; o < 16; o <<= 1) {
            int u = __shfl_up(si, o);
            if (lane >= o) si += u;
        }
        if (lane < 16) wexc[lane] = si - s;
        if (lane == 15) bsum[blockIdx.x] = si;
    }
    __syncthreads();
    if (i < NN) off[i] = wexc[wid] + incl - v;
}

__global__ __launch_bounds__(64) void k_scan2(const int* __restrict__ bsum,
        int* __restrict__ bexc, int* __restrict__ off)
{
    int lane = threadIdx.x;
    int v = (lane < NB) ? bsum[lane] : 0;
    int incl = v;
    #pragma unroll
    for (int o = 1; o < 64; o <<= 1) {
        int u = __shfl_up(incl, o);
        if (lane >= o) incl += u;
    }
    if (lane < NB) bexc[lane] = incl - v;
    if (lane == 63) off[NN] = incl;
}

__global__ __launch_bounds__(1024) void k_scan3(int* __restrict__ off,
        int* __restrict__ cur, const int* __restrict__ bexc)
{
    int i = blockIdx.x * 1024 + threadIdx.x;
    if (i < NN) {
        int o = off[i] + bexc[blockIdx.x];
        off[i] = o;
        cur[i] = o;
    }
}

__global__ void k_scatter(const int* __restrict__ src, const int* __restrict__ dst,
        const int* __restrict__ et, int* __restrict__ cur, int* __restrict__ srcP)
{
    int e = blockIdx.x * blockDim.x + threadIdx.x;
    if (e < EEN) {
        int p = atomicAdd(&cur[dst[e]], 1);
        srcP[p] = (src[e] << 4) | (et[e] << 28);
    }
}

// ---------------- per-edge-type attention bias tables (both layers) ----------
__global__ __launch_bounds__(192) void k_eetab2(const float* __restrict__ Eemb1,
        const float* __restrict__ We1, const float* __restrict__ ae1,
        float* __restrict__ ee1, const float* __restrict__ Eemb2,
        const float* __restrict__ We2, const float* __restrict__ ae2,
        float* __restrict__ ee2)
{
    const float* Eemb = blockIdx.x ? Eemb2 : Eemb1;
    const float* We   = blockIdx.x ? We2   : We1;
    const float* ae   = blockIdx.x ? ae2   : ae1;
    float* eetab      = blockIdx.x ? ee2   : ee1;
    __shared__ float t1[3 * 64];
    const int t = threadIdx.x;
    const int g = t & 63, h = t >> 6;
    const float* wrow = We + g * FEAT + h * EFD;
    const float* av   = ae + h * EFD;
    float s = 0.f;
    #pragma unroll 8
    for (int f = 0; f < EFD; ++f) s += wrow[f] * av[f];
    t1[h * 64 + g] = s;
    __syncthreads();
    if (t < 24) {
        int tt = t / 3, hh = t - tt * 3;
        float acc = 0.f;
        const float* em = Eemb + tt * EFD;
        const float* tv = t1 + hh * 64;
        #pragma unroll 8
        for (int g2 = 0; g2 < 64; ++g2) acc += em[g2] * tv[g2];
        eetab[tt * 3 + hh] = acc;
    }
}

// ---------------- fused edge-softmax + aggregation (wave per node) -----------
// srcP[e] = s*16 | et<<28 ; grid-stride over nodes; fast path for deg<=64
template<bool RES, bool FINAL>
__global__ __launch_bounds__(256) void k_attn_agg(const int* __restrict__ off,
        const int* __restrict__ srcP, const float4* __restrict__ el4,
        const float4* __restrict__ er4, const float* __restrict__ eetab,
        const ushort* __restrict__ featb, const ushort* __restrict__ resb,
        void* __restrict__ outv)
{
    __shared__ float4 sh[4][64];
    const int wid = threadIdx.x >> 6, lane = threadIdx.x & 63;
    const int hd = lane >> 4;                  // 0..2 gather head; 3 = idle
    const char* elc = (const char*)el4;
    const char* fb  = (const char*)featb + lane * 8;
    float4* shw = sh[wid];
    const float ee0 = eetab[hd == 1 ? 3 : 0];  // dummy preload (keeps eetab hot)

    for (int n = blockIdx.x * 4 + wid; n < NN; n += gridDim.x * 4) {
        const int beg = off[n], end = off[n + 1];
        const int deg = end - beg;
        const float4 erv = er4[n];
        float acc0 = 0.f, acc1 = 0.f, acc2 = 0.f, acc3 = 0.f;
        float i0, i1, i2;

        if (deg <= 64) {
            // ---- single-chunk fast path: no online rescaling ----
            const bool valid = lane < deg;
            int boff = 0;
            float l0 = -1e30f, l1 = -1e30f, l2 = -1e30f;
            if (valid) {
                int sp = srcP[beg + lane];
                int s16 = sp & SMASK;
                int tt = ((unsigned)sp) >> 28;
                float4 ev = *reinterpret_cast<const float4*>(elc + s16);
                l0 = ev.x + erv.x + eetab[tt*3+0];
                l1 = ev.y + erv.y + eetab[tt*3+1];
                l2 = ev.z + erv.z + eetab[tt*3+2];
                l0 = l0 > 0.f ? l0 : NEG_ * l0;
                l1 = l1 > 0.f ? l1 : NEG_ * l1;
                l2 = l2 > 0.f ? l2 : NEG_ * l2;
                boff = s16 * 24;               // s*384 bytes
            }
            float m0 = l0, m1 = l1, m2 = l2;
            #pragma unroll
            for (int o = 32; o > 0; o >>= 1) {
                m0 = fmaxf(m0, __shfl_xor(m0, o));
                m1 = fmaxf(m1, __shfl_xor(m1, o));
                m2 = fmaxf(m2, __shfl_xor(m2, o));
            }
            float p0 = valid ? __expf(l0 - m0) : 0.f;
            float p1 = valid ? __expf(l1 - m1) : 0.f;
            float p2 = valid ? __expf(l2 - m2) : 0.f;
            float d0 = p0, d1 = p1, d2 = p2;
            #pragma unroll
            for (int o = 32; o > 0; o >>= 1) {
                d0 += __shfl_xor(d0, o);
                d1 += __shfl_xor(d1, o);
                d2 += __shfl_xor(d2, o);
            }
            shw[lane] = make_float4(p0, p1, p2, __int_as_float(boff));
            i0 = 1.f / fmaxf(d0, EPSF);
            i1 = 1.f / fmaxf(d1, EPSF);
            i2 = 1.f / fmaxf(d2, EPSF);
            int j = 0;
            for (; j + 4 <= deg; j += 4) {
                float4 w0 = shw[j], w1 = shw[j+1], w2 = shw[j+2], w3 = shw[j+3];
                if (lane < 48) {
                    uint2 u0 = *reinterpret_cast<const uint2*>(fb + __float_as_int(w0.w));
                    uint2 u1 = *reinterpret_cast<const uint2*>(fb + __float_as_int(w1.w));
                    uint2 u2 = *reinterpret_cast<const uint2*>(fb + __float_as_int(w2.w));
                    uint2 u3 = *reinterpret_cast<const uint2*>(fb + __float_as_int(w3.w));
                    float g0 = hd == 0 ? w0.x : (hd == 1 ? w0.y : w0.z);
                    float g1 = hd == 0 ? w1.x : (hd == 1 ? w1.y : w1.z);
                    float g2 = hd == 0 ? w2.x : (hd == 1 ? w2.y : w2.z);
                    float g3 = hd == 0 ? w3.x : (hd == 1 ? w3.y : w3.z);
                    acc0 += g0*blo(u0.x) + g1*blo(u1.x) + g2*blo(u2.x) + g3*blo(u3.x);
                    acc1 += g0*bhi(u0.x) + g1*bhi(u1.x) + g2*bhi(u2.x) + g3*bhi(u3.x);
                    acc2 += g0*blo(u0.y) + g1*blo(u1.y) + g2*blo(u2.y) + g3*blo(u3.y);
                    acc3 += g0*bhi(u0.y) + g1*bhi(u1.y) + g2*bhi(u2.y) + g3*bhi(u3.y);
                }
            }
            for (; j < deg; ++j) {
                float4 wv = shw[j];
                if (lane < 48) {
                    uint2 u = *reinterpret_cast<const uint2*>(fb + __float_as_int(wv.w));
                    float g = hd == 0 ? wv.x : (hd == 1 ? wv.y : wv.z);
                    acc0 += g*blo(u.x); acc1 += g*bhi(u.x);
                    acc2 += g*blo(u.y); acc3 += g*bhi(u.y);
                }
            }
        } else {
            // ---- multi-chunk online-softmax path (rare) ----
            float m0 = -1e30f, m1 = -1e30f, m2 = -1e30f;
            float dl0 = 0.f, dl1 = 0.f, dl2 = 0.f;
            for (int c0 = beg; c0 < end; c0 += 64) {
                const int e = c0 + lane;
                const bool valid = e < end;
                int boff = 0;
                float l0 = -1e30f, l1 = -1e30f, l2 = -1e30f;
                if (valid) {
                    int sp = srcP[e];
                    int s16 = sp & SMASK;
                    int tt = ((unsigned)sp) >> 28;
                    float4 ev = *reinterpret_cast<const float4*>(elc + s16);
                    l0 = ev.x + erv.x + eetab[tt*3+0];
                    l1 = ev.y + erv.y + eetab[tt*3+1];
                    l2 = ev.z + erv.z + eetab[tt*3+2];
                    l0 = l0 > 0.f ? l0 : NEG_ * l0;
                    l1 = l1 > 0.f ? l1 : NEG_ * l1;
                    l2 = l2 > 0.f ? l2 : NEG_ * l2;
                    boff = s16 * 24;
                }
                float c0m = l0, c1m = l1, c2m = l2;
                #pragma unroll
                for (int o = 32; o > 0; o >>= 1) {
                    c0m = fmaxf(c0m, __shfl_xor(c0m, o));
                    c1m = fmaxf(c1m, __shfl_xor(c1m, o));
                    c2m = fmaxf(c2m, __shfl_xor(c2m, o));
                }
                const float nm0 = fmaxf(m0, c0m), nm1 = fmaxf(m1, c1m), nm2 = fmaxf(m2, c2m);
                const float sc0 = __expf(m0 - nm0), sc1 = __expf(m1 - nm1), sc2 = __expf(m2 - nm2);
                m0 = nm0; m1 = nm1; m2 = nm2;
                const float p0 = valid ? __expf(l0 - nm0) : 0.f;
                const float p1 = valid ? __expf(l1 - nm1) : 0.f;
                const float p2 = valid ? __expf(l2 - nm2) : 0.f;
                dl0 = dl0 * sc0 + p0; dl1 = dl1 * sc1 + p1; dl2 = dl2 * sc2 + p2;
                const float sch = hd == 0 ? sc0 : (hd == 1 ? sc1 : sc2);
                acc0 *= sch; acc1 *= sch; acc2 *= sch; acc3 *= sch;
                shw[lane] = make_float4(p0, p1, p2, __int_as_float(boff));
                const int cnt = min(64, end - c0);
                for (int j = 0; j < cnt; ++j) {
                    float4 wv = shw[j];
                    if (lane < 48) {
                        uint2 u = *reinterpret_cast<const uint2*>(fb + __float_as_int(wv.w));
                        float g = hd == 0 ? wv.x : (hd == 1 ? wv.y : wv.z);
                        acc0 += g*blo(u.x); acc1 += g*bhi(u.x);
                        acc2 += g*blo(u.y); acc3 += g*bhi(u.y);
                    }
                }
            }
            #pragma unroll
            for (int o = 32; o > 0; o >>= 1) {
                dl0 += __shfl_xor(dl0, o);
                dl1 += __shfl_xor(dl1, o);
                dl2 += __shfl_xor(dl2, o);
            }
            i0 = 1.f / fmaxf(dl0, EPSF);
            i1 = 1.f / fmaxf(dl1, EPSF);
            i2 = 1.f / fmaxf(dl2, EPSF);
        }

        const float inv = hd == 0 ? i0 : (hd == 1 ? i1 : i2);
        acc0 *= inv; acc1 *= inv; acc2 *= inv; acc3 *= inv;
        if (RES) {
            if (lane < 48) {
                uint2 r = *reinterpret_cast<const uint2*>((const char*)resb + (size_t)n * 384 + lane * 8);
                acc0 += blo(r.x); acc1 += bhi(r.x);
                acc2 += blo(r.y); acc3 += bhi(r.y);
            }
        }
        acc0 = acc0 > 0.f ? acc0 : expm1f(acc0);
        acc1 = acc1 > 0.f ? acc1 : expm1f(acc1);
        acc2 = acc2 > 0.f ? acc2 : expm1f(acc2);
        acc3 = acc3 > 0.f ? acc3 : expm1f(acc3);
        if (!FINAL) {
            if (lane < 48) {
                ushort4 o4;
                o4.x = (ushort)f2b(acc0); o4.y = (ushort)f2b(acc1);
                o4.z = (ushort)f2b(acc2); o4.w = (ushort)f2b(acc3);
                ((ushort4*)outv)[(size_t)n * 48 + lane] = o4;
            }
        } else {
            float b0 = __shfl(acc0, lane + 16), c0v = __shfl(acc0, lane + 32);
            float b1 = __shfl(acc1, lane + 16), c1v = __shfl(acc1, lane + 32);
            float b2 = __shfl(acc2, lane + 16), c2v = __shfl(acc2, lane + 32);
            float b3 = __shfl(acc3, lane + 16), c3v = __shfl(acc3, lane + 32);
            float mm0 = (acc0 + b0 + c0v) * (1.f / 3.f);
            float mm1 = (acc1 + b1 + c1v) * (1.f / 3.f);
            float mm2 = (acc2 + b2 + c2v) * (1.f / 3.f);
            float mm3 = (acc3 + b3 + c3v) * (1.f / 3.f);
            float ss = (lane < 16) ? (mm0*mm0 + mm1*mm1 + mm2*mm2 + mm3*mm3) : 0.f;
            #pragma unroll
            for (int o = 1; o < 16; o <<= 1) ss += __shfl_xor(ss, o);
            float nrm = sqrtf(ss);
            float invn = 1.f / fmaxf(nrm, EPSF);
            if (lane < 16) {
                ((float4*)outv)[(size_t)n * 16 + lane] =
                    make_float4(mm0 * invn, mm1 * invn, mm2 * invn, mm3 * invn);
            }
        }
    }
    (void)ee0;
}

extern "C" void kernel_launch(void* const* d_in, const int* in_sizes, int n_in,
                              void* d_out, int out_size, void* d_ws, size_t ws_size,
                              hipStream_t stream)
{
    const float* x     = (const float*)d_in[0];
    const int*   src   = (const int*)d_in[1];
    const int*   dst   = (const int*)d_in[2];
    const int*   efeat = (const int*)d_in[3];
    const float* W1    = (const float*)d_in[4];
    const float* Eemb1 = (const float*)d_in[5];
    const float* We1   = (const float*)d_in[6];
    const float* al1   = (const float*)d_in[7];
    const float* ar1   = (const float*)d_in[8];
    const float* ae1   = (const float*)d_in[9];
    const float* W2    = (const float*)d_in[10];
    const float* Eemb2 = (const float*)d_in[11];
    const float* We2   = (const float*)d_in[12];
    const float* al2   = (const float*)d_in[13];
    const float* ar2   = (const float*)d_in[14];
    const float* ae2   = (const float*)d_in[15];
    const float* Wres2 = (const float*)d_in[16];

    char* w = (char*)d_ws;
    auto alloc = [&](size_t bytes) {
        char* p = w;
        w += (bytes + 255) & ~(size_t)255;
        return p;
    };
    ushort* featb = (ushort*)alloc((size_t)NN * FEAT * 2);   // gemm out (bf16)
    ushort* h1b   = (ushort*)alloc((size_t)NN * FEAT * 2);   // layer1 out (bf16)
    ushort* resb  = (ushort*)alloc((size_t)NN * FEAT * 2);   // residual (bf16)
    float4* el4   = (float4*)alloc((size_t)NN * 16);
    float4* er4   = (float4*)alloc((size_t)NN * 16);
    int*    deg   = (int*)alloc((size_t)NN * 4);
    int*    off   = (int*)alloc((size_t)(NN + 1) * 4);
    int*    cur   = (int*)alloc((size_t)NN * 4);
    int*    srcP  = (int*)alloc((size_t)EEN * 4);
    int*    bsum  = (int*)alloc(64 * 4);
    int*    bexc  = (int*)alloc(64 * 4);
    ushort* w1bt  = (ushort*)alloc((size_t)FEAT * INF_ * 2);
    ushort* w2bt  = (ushort*)alloc((size_t)FEAT * FEAT * 2);
    ushort* wrbt  = (ushort*)alloc((size_t)FEAT * FEAT * 2);
    float*  ee1   = (float*)alloc(24 * 4);
    float*  ee2   = (float*)alloc(24 * 4);

    hipMemsetAsync(deg, 0, (size_t)NN * 4, stream);

    const int eb = (EEN + 255) / 256;
    k_hist<<<eb, 256, 0, stream>>>(dst, deg);
    k_scan1<<<NB, 1024, 0, stream>>>(deg, off, bsum);
    k_scan2<<<1, 64, 0, stream>>>(bsum, bexc, off);
    k_scan3<<<NB, 1024, 0, stream>>>(off, cur, bexc);
    k_scatter<<<eb, 256, 0, stream>>>(src, dst, efeat, cur, srcP);
    k_eetab2<<<2, 192, 0, stream>>>(Eemb1, We1, ae1, ee1, Eemb2, We2, ae2, ee2);
    const int wtot = FEAT * INF_ + 2 * FEAT * FEAT;
    k_wtrans3<<<(wtot + 255) / 256, 256, 0, stream>>>(W1, w1bt, W2, w2bt, Wres2, wrbt);

    const int gb = (NN + 63) / 64;
    // ---- layer 1 ----
    gemm_mfma<true, false><<<gb, 256, 0, stream>>>(x, w1bt, nullptr, featb,
            nullptr, el4, er4, al1, ar1, NN, INF_);
    k_attn_agg<false, false><<<2048, 256, 0, stream>>>(off, srcP, el4, er4, ee1,
            featb, nullptr, h1b);
    // ---- layer 2 (W2 and Wres in one pass) ----
    gemm_mfma<false, true><<<gb, 256, 0, stream>>>(h1b, w2bt, wrbt, featb,
            resb, el4, er4, al2, ar2, NN, FEAT);
    k_attn_agg<true, true><<<2048, 256, 0, stream>>>(off, srcP, el4, er4, ee2,
            featb, resb, (float*)d_out);
}

// Round 7
// 266.772 us; speedup vs baseline: 3.1980x; 1.0886x over previous
//
#include <hip/hip_runtime.h>
#include <cstdint>
#include <cstddef>

#define NN   50000
#define EEN  800000
#define INF_ 256
#define HH   3
#define FEAT 192   // H*D
#define EFD  64
#define NEG_ 0.2f
#define EPSF 1e-12f
#define SMASK 0x0FFFFFF0   // s*16 field in srcP
#define NB   ((NN + 1023) / 1024)

typedef __attribute__((ext_vector_type(8))) short short8;
typedef __attribute__((ext_vector_type(4))) float f32x4;

static __device__ __forceinline__ float4 ld4(const float* p) {
    return *reinterpret_cast<const float4*>(p);
}
static __device__ __forceinline__ uint f2b(float f) {
    union { float f; uint32_t u; } v; v.f = f;
    uint32_t u = v.u;
    return (u + 0x7FFFu + ((u >> 16) & 1u)) >> 16;
}
static __device__ __forceinline__ uint pack2(float a, float b) {
    return f2b(a) | (f2b(b) << 16);
}
static __device__ __forceinline__ float blo(uint u) {
    return __uint_as_float(u << 16);
}
static __device__ __forceinline__ float bhi(uint u) {
    return __uint_as_float(u & 0xFFFF0000u);
}

// ---------------- weight transpose+convert (all 3 weights, one launch) -------
__global__ __launch_bounds__(256) void k_wtrans3(const float* __restrict__ W1,
        ushort* __restrict__ o1, const float* __restrict__ W2,
        ushort* __restrict__ o2, const float* __restrict__ W3,
        ushort* __restrict__ o3)
{
    int idx = blockIdx.x * blockDim.x + threadIdx.x;
    if (idx < FEAT * INF_) {
        int n = idx / INF_, k = idx - n * INF_;
        o1[idx] = (ushort)f2b(W1[(size_t)k * FEAT + n]);
    } else if (idx < FEAT * INF_ + FEAT * FEAT) {
        int i = idx - FEAT * INF_;
        int n = i / FEAT, k = i - n * FEAT;
        o2[i] = (ushort)f2b(W2[(size_t)k * FEAT + n]);
    } else if (idx < FEAT * INF_ + 2 * FEAT * FEAT) {
        int i = idx - FEAT * INF_ - FEAT * FEAT;
        int n = i / FEAT, k = i - n * FEAT;
        o3[i] = (ushort)f2b(W3[(size_t)k * FEAT + n]);
    }
}

// ---------------- MFMA GEMM: 64-row tile, full-N(192), optional dual-B -------
// always computes el/er epilogue from the first (featb) product
#define LDA 40   // padded LDS row stride (ushort)
template<bool AF32, bool DUAL>
__global__ __launch_bounds__(256) void gemm_mfma(const void* __restrict__ Av,
        const ushort* __restrict__ BT, const ushort* __restrict__ BT2,
        ushort* __restrict__ Cb, ushort* __restrict__ resb,
        float4* __restrict__ el4, float4* __restrict__ er4,
        const float* __restrict__ al, const float* __restrict__ ar,
        int M, int K)
{
    __shared__ ushort As[64 * LDA];
    __shared__ ushort Bs[192 * LDA];
    __shared__ ushort Bs2[DUAL ? 192 * LDA : 16];
    const int t = threadIdx.x;
    const int lane = t & 63, w = t >> 6;
    const int bm = blockIdx.x * 64;
    const int fr = lane & 15;
    const int fq = lane >> 4;
    const int fg = fq * 8;
    const int arow = t >> 2;           // 0..63
    const int acol = (t & 3) * 8;
    const int brow = t >> 2;
    const int bcol = (t & 3) * 8;

    f32x4 acc[12], acc2[DUAL ? 12 : 1];
    #pragma unroll
    for (int c = 0; c < 12; ++c) acc[c] = (f32x4){0.f, 0.f, 0.f, 0.f};
    if (DUAL) {
        #pragma unroll
        for (int c = 0; c < 12; ++c) acc2[c] = (f32x4){0.f, 0.f, 0.f, 0.f};
    }

    const int ga = bm + arow;
    for (int k0 = 0; k0 < K; k0 += 32) {
        uint4 u0 = make_uint4(0,0,0,0);
        if (AF32) {
            if (ga < M) {
                const float* ap = (const float*)Av + (size_t)ga * K + k0 + acol;
                float4 f0 = ld4(ap), f1 = ld4(ap + 4);
                u0 = make_uint4(pack2(f0.x,f0.y), pack2(f0.z,f0.w),
                                pack2(f1.x,f1.y), pack2(f1.z,f1.w));
            }
        } else {
            if (ga < M)
                u0 = *reinterpret_cast<const uint4*>((const ushort*)Av + (size_t)ga * K + k0 + acol);
        }
        *reinterpret_cast<uint4*>(As + arow * LDA + acol) = u0;
        #pragma unroll
        for (int j = 0; j < 3; ++j) {
            uint4 bv = *reinterpret_cast<const uint4*>(BT + (size_t)(j * 64 + brow) * K + k0 + bcol);
            *reinterpret_cast<uint4*>(Bs + (j * 64 + brow) * LDA + bcol) = bv;
            if (DUAL) {
                uint4 b2 = *reinterpret_cast<const uint4*>(BT2 + (size_t)(j * 64 + brow) * K + k0 + bcol);
                *reinterpret_cast<uint4*>(Bs2 + (j * 64 + brow) * LDA + bcol) = b2;
            }
        }
        __syncthreads();
        short8 afr = *reinterpret_cast<const short8*>(As + (w * 16 + fr) * LDA + fg);
        #pragma unroll
        for (int c = 0; c < 12; ++c) {
            short8 bfr = *reinterpret_cast<const short8*>(Bs + (c * 16 + fr) * LDA + fg);
            acc[c] = __builtin_amdgcn_mfma_f32_16x16x32_bf16(afr, bfr, acc[c], 0, 0, 0);
            if (DUAL) {
                short8 b2 = *reinterpret_cast<const short8*>(Bs2 + (c * 16 + fr) * LDA + fg);
                acc2[c] = __builtin_amdgcn_mfma_f32_16x16x32_bf16(afr, b2, acc2[c], 0, 0, 0);
            }
        }
        __syncthreads();
    }
    #pragma unroll
    for (int j = 0; j < 4; ++j) {
        int row = bm + w * 16 + fq * 4 + j;
        if (row < M) {
            #pragma unroll
            for (int c = 0; c < 12; ++c) {
                Cb[(size_t)row * FEAT + c * 16 + fr] = (ushort)f2b(acc[c][j]);
                if (DUAL)
                    resb[(size_t)row * FEAT + c * 16 + fr] = (ushort)f2b(acc2[c][j]);
            }
        }
    }
    // fused el/er epilogue
    float alv[12], arv[12];
    #pragma unroll
    for (int c = 0; c < 12; ++c) {
        alv[c] = al[c * 16 + fr];
        arv[c] = ar[c * 16 + fr];
    }
    #pragma unroll
    for (int j = 0; j < 4; ++j) {
        int row = bm + w * 16 + fq * 4 + j;
        float pl0 = 0.f, pl1 = 0.f, pl2 = 0.f;
        float pr0 = 0.f, pr1 = 0.f, pr2 = 0.f;
        #pragma unroll
        for (int c = 0; c < 4; ++c)  { pl0 += acc[c][j]*alv[c];  pr0 += acc[c][j]*arv[c]; }
        #pragma unroll
        for (int c = 4; c < 8; ++c)  { pl1 += acc[c][j]*alv[c];  pr1 += acc[c][j]*arv[c]; }
        #pragma unroll
        for (int c = 8; c < 12; ++c) { pl2 += acc[c][j]*alv[c];  pr2 += acc[c][j]*arv[c]; }
        #pragma unroll
        for (int o = 1; o < 16; o <<= 1) {
            pl0 += __shfl_xor(pl0, o); pl1 += __shfl_xor(pl1, o); pl2 += __shfl_xor(pl2, o);
            pr0 += __shfl_xor(pr0, o); pr1 += __shfl_xor(pr1, o); pr2 += __shfl_xor(pr2, o);
        }
        if (fr == 0 && row < M) {
            el4[row] = make_float4(pl0, pl1, pl2, 0.f);
            er4[row] = make_float4(pr0, pr1, pr2, 0.f);
        }
    }
}

// ---------------- CSR build --------------------------------------------------
__global__ void k_hist(const int* __restrict__ dst, int* __restrict__ deg) {
    int e = blockIdx.x * blockDim.x + threadIdx.x;
    if (e < EEN) atomicAdd(&deg[dst[e]], 1);
}

__global__ __launch_bounds__(1024) void k_scan1(const int* __restrict__ deg,
        int* __restrict__ off, int* __restrict__ bsum)
{
    __shared__ int wsums[16];
    __shared__ int wexc[16];
    const int tid = threadIdx.x;
    const int lane = tid & 63, wid = tid >> 6;
    int i = blockIdx.x * 1024 + tid;
    int v = (i < NN) ? deg[i] : 0;
    int incl = v;
    #pragma unroll
    for (int o = 1; o < 64; o <<= 1) {
        int u = __shfl_up(incl, o);
        if (lane >= o) incl += u;
    }
    if (lane == 63) wsums[wid] = incl;
    __syncthreads();
    if (wid == 0) {
        int s = (lane < 16) ? wsums[lane] : 0;
        int si = s;
        #pragma unroll
        for (int o = 1; o < 16; o <<= 1) {
            int u = __shfl_up(si, o);
            if (lane >= o) si += u;
        }
        if (lane < 16) wexc[lane] = si - s;
        if (lane == 15) bsum[blockIdx.x] = si;
    }
    __syncthreads();
    if (i < NN) off[i] = wexc[wid] + incl - v;
}

__global__ __launch_bounds__(64) void k_scan2(const int* __restrict__ bsum,
        int* __restrict__ bexc, int* __restrict__ off)
{
    int lane = threadIdx.x;
    int v = (lane < NB) ? bsum[lane] : 0;
    int incl = v;
    #pragma unroll
    for (int o = 1; o < 64; o <<= 1) {
        int u = __shfl_up(incl, o);
        if (lane >= o) incl += u;
    }
    if (lane < NB) bexc[lane] = incl - v;
    if (lane == 63) off[NN] = incl;
}

__global__ __launch_bounds__(1024) void k_scan3(int* __restrict__ off,
        int* __restrict__ cur, const int* __restrict__ bexc)
{
    int i = blockIdx.x * 1024 + threadIdx.x;
    if (i < NN) {
        int o = off[i] + bexc[blockIdx.x];
        off[i] = o;
        cur[i] = o;
    }
}

__global__ void k_scatter(const int* __restrict__ src, const int* __restrict__ dst,
        const int* __restrict__ et, int* __restrict__ cur, int* __restrict__ srcP)
{
    int e = blockIdx.x * blockDim.x + threadIdx.x;
    if (e < EEN) {
        int p = atomicAdd(&cur[dst[e]], 1);
        srcP[p] = (src[e] << 4) | (et[e] << 28);
    }
}

// ---------------- per-edge-type attention bias tables (both layers) ----------
__global__ __launch_bounds__(192) void k_eetab2(const float* __restrict__ Eemb1,
        const float* __restrict__ We1, const float* __restrict__ ae1,
        float* __restrict__ ee1, const float* __restrict__ Eemb2,
        const float* __restrict__ We2, const float* __restrict__ ae2,
        float* __restrict__ ee2)
{
    const float* Eemb = blockIdx.x ? Eemb2 : Eemb1;
    const float* We   = blockIdx.x ? We2   : We1;
    const float* ae   = blockIdx.x ? ae2   : ae1;
    float* eetab      = blockIdx.x ? ee2   : ee1;
    __shared__ float t1[3 * 64];
    const int t = threadIdx.x;
    const int g = t & 63, h = t >> 6;
    const float* wrow = We + g * FEAT + h * EFD;
    const float* av   = ae + h * EFD;
    float s = 0.f;
    #pragma unroll 8
    for (int f = 0; f < EFD; ++f) s += wrow[f] * av[f];
    t1[h * 64 + g] = s;
    __syncthreads();
    if (t < 24) {
        int tt = t / 3, hh = t - tt * 3;
        float acc = 0.f;
        const float* em = Eemb + tt * EFD;
        const float* tv = t1 + hh * 64;
        #pragma unroll 8
        for (int g2 = 0; g2 < 64; ++g2) acc += em[g2] * tv[g2];
        eetab[tt * 3 + hh] = acc;
    }
}

// ---------------- fused edge-softmax + aggregation (wave per node) -----------
// No max-subtraction (logits bounded by construction): p = exp(l) directly,
// accumulate unnormalized, normalize once at the end. One unified loop.
// LDS layout per edge j: 6 floats = {p0,boff, p1,boff, p2,boff} -> gather loop
// reads ONE b64 (weight, byte-offset) selected by head via address.
template<bool RES, bool FINAL>
__global__ __launch_bounds__(256) void k_attn_agg(const int* __restrict__ off,
        const int* __restrict__ srcP, const float4* __restrict__ el4,
        const float4* __restrict__ er4, const float* __restrict__ eetab,
        const ushort* __restrict__ featb, const ushort* __restrict__ resb,
        void* __restrict__ outv)
{
    __shared__ float shw[4][64 * 6];
    __shared__ float eet[24];
    const int wid = threadIdx.x >> 6, lane = threadIdx.x & 63;
    if (threadIdx.x < 24) eet[threadIdx.x] = eetab[threadIdx.x];
    __syncthreads();
    const int n = blockIdx.x * 4 + wid;
    if (n >= NN) return;
    const int hd = lane >> 4;                  // 0..2 gather head; 3 = idle
    const char* elc = (const char*)el4;
    const char* fb  = (const char*)featb + lane * 8;
    float* sw = shw[wid];

    const int beg = off[n], end = off[n + 1];
    const float4 erv = er4[n];
    float acc0 = 0.f, acc1 = 0.f, acc2 = 0.f, acc3 = 0.f;
    float dl0 = 0.f, dl1 = 0.f, dl2 = 0.f;

    for (int c0 = beg; c0 < end; c0 += 64) {
        const int e = c0 + lane;
        float p0 = 0.f, p1 = 0.f, p2 = 0.f;
        int boff = 0;
        if (e < end) {
            int sp = srcP[e];
            int s16 = sp & SMASK;
            int tt = ((unsigned)sp) >> 28;
            float4 ev = *reinterpret_cast<const float4*>(elc + s16);
            float l0 = ev.x + erv.x + eet[tt*3+0];
            float l1 = ev.y + erv.y + eet[tt*3+1];
            float l2 = ev.z + erv.z + eet[tt*3+2];
            l0 = l0 > 0.f ? l0 : NEG_ * l0;
            l1 = l1 > 0.f ? l1 : NEG_ * l1;
            l2 = l2 > 0.f ? l2 : NEG_ * l2;
            p0 = __expf(l0); p1 = __expf(l1); p2 = __expf(l2);
            boff = s16 * 24;                   // s*384 bytes into featb
        }
        dl0 += p0; dl1 += p1; dl2 += p2;
        const float bf = __int_as_float(boff);
        float* sl = sw + lane * 6;
        *reinterpret_cast<float2*>(sl + 0) = make_float2(p0, bf);
        *reinterpret_cast<float2*>(sl + 2) = make_float2(p1, bf);
        *reinterpret_cast<float2*>(sl + 4) = make_float2(p2, bf);
        const int cnt = min(64, end - c0);
        const float* swh = sw + hd * 2;
        int j = 0;
        for (; j + 4 <= cnt; j += 4) {
            if (lane < 48) {
                float2 g0 = *reinterpret_cast<const float2*>(swh + (j+0)*6);
                float2 g1 = *reinterpret_cast<const float2*>(swh + (j+1)*6);
                float2 g2 = *reinterpret_cast<const float2*>(swh + (j+2)*6);
                float2 g3 = *reinterpret_cast<const float2*>(swh + (j+3)*6);
                uint2 u0 = *reinterpret_cast<const uint2*>(fb + __float_as_int(g0.y));
                uint2 u1 = *reinterpret_cast<const uint2*>(fb + __float_as_int(g1.y));
                uint2 u2 = *reinterpret_cast<const uint2*>(fb + __float_as_int(g2.y));
                uint2 u3 = *reinterpret_cast<const uint2*>(fb + __float_as_int(g3.y));
                acc0 += g0.x*blo(u0.x) + g1.x*blo(u1.x) + g2.x*blo(u2.x) + g3.x*blo(u3.x);
                acc1 += g0.x*bhi(u0.x) + g1.x*bhi(u1.x) + g2.x*bhi(u2.x) + g3.x*bhi(u3.x);
                acc2 += g0.x*blo(u0.y) + g1.x*blo(u1.y) + g2.x*blo(u2.y) + g3.x*blo(u3.y);
                acc3 += g0.x*bhi(u0.y) + g1.x*bhi(u1.y) + g2.x*bhi(u2.y) + g3.x*bhi(u3.y);
            }
        }
        for (; j < cnt; ++j) {
            if (lane < 48) {
                float2 gv = *reinterpret_cast<const float2*>(swh + j*6);
                uint2 u = *reinterpret_cast<const uint2*>(fb + __float_as_int(gv.y));
                acc0 += gv.x*blo(u.x); acc1 += gv.x*bhi(u.x);
                acc2 += gv.x*blo(u.y); acc3 += gv.x*bhi(u.y);
            }
        }
    }
    #pragma unroll
    for (int o = 32; o > 0; o >>= 1) {
        dl0 += __shfl_xor(dl0, o);
        dl1 += __shfl_xor(dl1, o);
        dl2 += __shfl_xor(dl2, o);
    }
    const float den = hd == 0 ? dl0 : (hd == 1 ? dl1 : dl2);
    const float inv = 1.f / fmaxf(den, EPSF);
    acc0 *= inv; acc1 *= inv; acc2 *= inv; acc3 *= inv;
    if (RES) {
        if (lane < 48) {
            uint2 r = *reinterpret_cast<const uint2*>((const char*)resb + (size_t)n * 384 + lane * 8);
            acc0 += blo(r.x); acc1 += bhi(r.x);
            acc2 += blo(r.y); acc3 += bhi(r.y);
        }
    }
    acc0 = acc0 > 0.f ? acc0 : expm1f(acc0);
    acc1 = acc1 > 0.f ? acc1 : expm1f(acc1);
    acc2 = acc2 > 0.f ? acc2 : expm1f(acc2);
    acc3 = acc3 > 0.f ? acc3 : expm1f(acc3);
    if (!FINAL) {
        if (lane < 48) {
            ushort4 o4;
            o4.x = (ushort)f2b(acc0); o4.y = (ushort)f2b(acc1);
            o4.z = (ushort)f2b(acc2); o4.w = (ushort)f2b(acc3);
            ((ushort4*)outv)[(size_t)n * 48 + lane] = o4;
        }
    } else {
        float b0 = __shfl(acc0, lane + 16), c0v = __shfl(acc0, lane + 32);
        float b1 = __shfl(acc1, lane + 16), c1v = __shfl(acc1, lane + 32);
        float b2 = __shfl(acc2, lane + 16), c2v = __shfl(acc2, lane + 32);
        float b3 = __shfl(acc3, lane + 16), c3v = __shfl(acc3, lane + 32);
        float mm0 = (acc0 + b0 + c0v) * (1.f / 3.f);
        float mm1 = (acc1 + b1 + c1v) * (1.f / 3.f);
        float mm2 = (acc2 + b2 + c2v) * (1.f / 3.f);
        float mm3 = (acc3 + b3 + c3v) * (1.f / 3.f);
        float ss = (lane < 16) ? (mm0*mm0 + mm1*mm1 + mm2*mm2 + mm3*mm3) : 0.f;
        #pragma unroll
        for (int o = 1; o < 16; o <<= 1) ss += __shfl_xor(ss, o);
        float nrm = sqrtf(ss);
        float invn = 1.f / fmaxf(nrm, EPSF);
        if (lane < 16) {
            ((float4*)outv)[(size_t)n * 16 + lane] =
                make_float4(mm0 * invn, mm1 * invn, mm2 * invn, mm3 * invn);
        }
    }
}

extern "C" void kernel_launch(void* const* d_in, const int* in_sizes, int n_in,
                              void* d_out, int out_size, void* d_ws, size_t ws_size,
                              hipStream_t stream)
{
    const float* x     = (const float*)d_in[0];
    const int*   src   = (const int*)d_in[1];
    const int*   dst   = (const int*)d_in[2];
    const int*   efeat = (const int*)d_in[3];
    const float* W1    = (const float*)d_in[4];
    const float* Eemb1 = (const float*)d_in[5];
    const float* We1   = (const float*)d_in[6];
    const float* al1   = (const float*)d_in[7];
    const float* ar1   = (const float*)d_in[8];
    const float* ae1   = (const float*)d_in[9];
    const float* W2    = (const float*)d_in[10];
    const float* Eemb2 = (const float*)d_in[11];
    const float* We2   = (const float*)d_in[12];
    const float* al2   = (const float*)d_in[13];
    const float* ar2   = (const float*)d_in[14];
    const float* ae2   = (const float*)d_in[15];
    const float* Wres2 = (const float*)d_in[16];

    char* w = (char*)d_ws;
    auto alloc = [&](size_t bytes) {
        char* p = w;
        w += (bytes + 255) & ~(size_t)255;
        return p;
    };
    ushort* featb = (ushort*)alloc((size_t)NN * FEAT * 2);   // gemm out (bf16)
    ushort* h1b   = (ushort*)alloc((size_t)NN * FEAT * 2);   // layer1 out (bf16)
    ushort* resb  = (ushort*)alloc((size_t)NN * FEAT * 2);   // residual (bf16)
    float4* el4   = (float4*)alloc((size_t)NN * 16);
    float4* er4   = (float4*)alloc((size_t)NN * 16);
    int*    deg   = (int*)alloc((size_t)NN * 4);
    int*    off   = (int*)alloc((size_t)(NN + 1) * 4);
    int*    cur   = (int*)alloc((size_t)NN * 4);
    int*    srcP  = (int*)alloc((size_t)EEN * 4);
    int*    bsum  = (int*)alloc(64 * 4);
    int*    bexc  = (int*)alloc(64 * 4);
    ushort* w1bt  = (ushort*)alloc((size_t)FEAT * INF_ * 2);
    ushort* w2bt  = (ushort*)alloc((size_t)FEAT * FEAT * 2);
    ushort* wrbt  = (ushort*)alloc((size_t)FEAT * FEAT * 2);
    float*  ee1   = (float*)alloc(24 * 4);
    float*  ee2   = (float*)alloc(24 * 4);

    hipMemsetAsync(deg, 0, (size_t)NN * 4, stream);

    const int eb = (EEN + 255) / 256;
    k_hist<<<eb, 256, 0, stream>>>(dst, deg);
    k_scan1<<<NB, 1024, 0, stream>>>(deg, off, bsum);
    k_scan2<<<1, 64, 0, stream>>>(bsum, bexc, off);
    k_scan3<<<NB, 1024, 0, stream>>>(off, cur, bexc);
    k_scatter<<<eb, 256, 0, stream>>>(src, dst, efeat, cur, srcP);
    k_eetab2<<<2, 192, 0, stream>>>(Eemb1, We1, ae1, ee1, Eemb2, We2, ae2, ee2);
    const int wtot = FEAT * INF_ + 2 * FEAT * FEAT;
    k_wtrans3<<<(wtot + 255) / 256, 256, 0, stream>>>(W1, w1bt, W2, w2bt, Wres2, wrbt);

    const int gb  = (NN + 63) / 64;
    const int nb4 = (NN + 3) / 4;
    // ---- layer 1 ----
    gemm_mfma<true, false><<<gb, 256, 0, stream>>>(x, w1bt, nullptr, featb,
            nullptr, el4, er4, al1, ar1, NN, INF_);
    k_attn_agg<false, false><<<nb4, 256, 0, stream>>>(off, srcP, el4, er4, ee1,
            featb, nullptr, h1b);
    // ---- layer 2 (W2 and Wres in one pass) ----
    gemm_mfma<false, true><<<gb, 256, 0, stream>>>(h1b, w2bt, wrbt, featb,
            resb, el4, er4, al2, ar2, NN, FEAT);
    k_attn_agg<true, true><<<nb4, 256, 0, stream>>>(off, srcP, el4, er4, ee2,
            featb, resb, (float*)d_out);
}